// Round 8
// baseline (416.777 us; speedup 1.0000x reference)
//
#include <hip/hip_runtime.h>
#include <hip/hip_bf16.h>
#include <math.h>

// Problem constants (fixed by the reference)
#define MV   100000          // voxels
#define NQ   8192            // queries
#define KN   32              // neighbors per query
#define CH   256             // channels
#define NH   8               // heads
#define DHD  32              // head dim
#define FFD  512             // FF hidden
#define NG   (NQ*KN)         // 262144 gathered rows
#define QPW  37              // 15+15+7 rel-pos columns per head (q-side)
#define QPN  (NH*QPW)        // 296
#define QPL  320             // padded qp row stride (multiple of 64)
#define ASTR 40              // padded LDS stride for k_mm

typedef __bf16 bf16x8 __attribute__((ext_vector_type(8)));
typedef float  f32x4  __attribute__((ext_vector_type(4)));

__device__ __forceinline__ float bf2f(unsigned short u) {
    return __uint_as_float(((unsigned int)u) << 16);
}
__device__ __forceinline__ unsigned short f2bf(float f) {
    unsigned int x = __float_as_uint(f);
    unsigned int r = x + 0x7FFFu + ((x >> 16) & 1u);   // RNE
    return (unsigned short)(r >> 16);
}
// async global->LDS, 16 B per lane; LDS dest = wave-uniform base + lane*16
__device__ __forceinline__ void glds16(const unsigned short* g, unsigned short* l) {
    __builtin_amdgcn_global_load_lds(
        (const __attribute__((address_space(1))) void*)g,
        (__attribute__((address_space(3))) void*)l, 16, 0, 0);
}

// ---------------------------------------------------------------------------
// k_detect_mask: gather_mask may ship as int32 (0/1) or raw 1-byte bools.
// ---------------------------------------------------------------------------
__global__ __launch_bounds__(256) void k_detect_mask(const unsigned char* __restrict__ raw,
                                                     int* __restrict__ flags) {
    __shared__ int any;
    if (threadIdx.x == 0) any = 0;
    __syncthreads();
    const uint4* p = (const uint4*)raw;             // NG bytes = 16384 uint4
    int i = blockIdx.x * 256 + threadIdx.x;
    uint4 v = p[i];
    if ((v.x | v.y | v.z | v.w) & 0xFFFFFF00u) any = 1;
    __syncthreads();
    if (threadIdx.x == 0) flags[blockIdx.x] = any;
}

// ---------------------------------------------------------------------------
// k_prep: int mask (layout-adaptive) + touched-voxel map + bf16 col-major
// (B-layout) weights + bkv = [b_k|b_v] + zbias.
// touched[] must be zeroed before this kernel (hipMemsetAsync).
// ---------------------------------------------------------------------------
__global__ __launch_bounds__(256) void k_prep(const float* __restrict__ w_k,
                                              const float* __restrict__ w_v,
                                              const float* __restrict__ w_ff1,
                                              const float* __restrict__ w_ff2,
                                              const float* __restrict__ w_proj,
                                              const float* __restrict__ w_q,
                                              const float* __restrict__ b_k,
                                              const float* __restrict__ b_v,
                                              const float* __restrict__ pos_qx,
                                              const float* __restrict__ pos_qy,
                                              const float* __restrict__ pos_qz,
                                              const void* __restrict__ mask_raw,
                                              const int* __restrict__ gidx,
                                              const int* __restrict__ flags,
                                              unsigned short* __restrict__ w_kv_t,
                                              unsigned short* __restrict__ w1_t,
                                              unsigned short* __restrict__ w2_t,
                                              unsigned short* __restrict__ wp_t,
                                              unsigned short* __restrict__ wq_t,
                                              unsigned short* __restrict__ wqp_t,
                                              float* __restrict__ bkv,
                                              float* __restrict__ zbias,
                                              int* __restrict__ mask_i,
                                              unsigned char* __restrict__ touched) {
    __shared__ int bl;
    if (threadIdx.x == 0) {
        int a = 0;
        #pragma unroll 8
        for (int i = 0; i < 64; i++) a |= flags[i];
        bl = a;
    }
    __syncthreads();
    int byteLayout = bl;
    int idx = blockIdx.x * 256 + threadIdx.x;       // grid 1024 -> 262144
    if (blockIdx.x == 0 && threadIdx.x < 512)
        bkv[threadIdx.x] = (threadIdx.x < 256) ? b_k[threadIdx.x]
                                               : b_v[threadIdx.x - 256];
    if (idx < QPL) zbias[idx] = 0.f;
    if (idx < NG) {
        int mv = byteLayout ? (int)((const unsigned char*)mask_raw)[idx]
                            : ((const int*)mask_raw)[idx];
        mask_i[idx] = (mv != 0) ? 1 : 0;
        if (mv == 0) touched[gidx[idx]] = 1;        // idempotent byte store
    }
    if (idx < 512 * 256) {
        int col = idx >> 8, j = idx & 255;
        float v = (col < 256) ? w_k[j * 256 + col] : w_v[j * 256 + (col - 256)];
        w_kv_t[idx] = f2bf(v);
    }
    if (idx < 512 * 256) {
        int n = idx >> 8, k = idx & 255;
        w1_t[idx] = f2bf(w_ff1[k * FFD + n]);
    }
    if (idx < 256 * 512) {
        int n = idx >> 9, k = idx & 511;
        w2_t[idx] = f2bf(w_ff2[k * CH + n]);
    }
    if (idx < 256 * 256) {
        int n = idx >> 8, k = idx & 255;
        wp_t[idx] = f2bf(w_proj[k * CH + n]);
        wq_t[idx] = f2bf(w_q[k * CH + n]);
    }
    if (idx < QPL * 256) {                          // wqp_t[col][k]
        int col = idx >> 8, k = idx & 255;
        float v = 0.f;
        if (col < QPN) {
            int h = col / QPW, r = col % QPW;
            int h2 = k >> 5, d = k & 31;
            if (h2 == h) {
                if (r < 15)      v = pos_qx[(h * DHD + d) * 15 + r];
                else if (r < 30) v = pos_qy[(h * DHD + d) * 15 + (r - 15)];
                else             v = pos_qz[(h * DHD + d) * 7  + (r - 30)];
            }
        }
        wqp_t[idx] = f2bf(v);
    }
}

// ---------------------------------------------------------------------------
// k_posc: comb[h][rx][ry][rz][d] = pos_kx[h][d][rx]+pos_ky[h][d][ry]+pos_kz[h][d][rz]
// ---------------------------------------------------------------------------
__global__ __launch_bounds__(256) void k_posc(const float* __restrict__ pos_kx,
                                              const float* __restrict__ pos_ky,
                                              const float* __restrict__ pos_kz,
                                              float* __restrict__ comb) {
    int idx = blockIdx.x * 256 + threadIdx.x;
    if (idx >= 8 * 15 * 15 * 7 * 32) return;
    int d = idx & 31, r = idx >> 5;
    int rz = r % 7;  r /= 7;
    int ry = r % 15; r /= 15;
    int rx = r % 15; int h = r / 15;
    comb[idx] = pos_kx[(h * DHD + d) * 15 + rx]
              + pos_ky[(h * DHD + d) * 15 + ry]
              + pos_kz[(h * DHD + d) * 7  + rz];
}

// ---------------------------------------------------------------------------
// k_ln: LayerNorm rows of x[nrows][256] -> bf16. One wave per row.
// ---------------------------------------------------------------------------
__global__ __launch_bounds__(256) void k_ln(const float* __restrict__ x,
                                            const float* __restrict__ g,
                                            const float* __restrict__ b,
                                            unsigned short* __restrict__ o,
                                            int nrows) {
    int wid = threadIdx.x >> 6, lane = threadIdx.x & 63;
    int row = blockIdx.x * 4 + wid;
    if (row >= nrows) return;
    const float4 v = *(const float4*)(x + (size_t)row * CH + lane * 4);
    float s  = v.x + v.y + v.z + v.w;
    float sq = v.x * v.x + v.y * v.y + v.z * v.z + v.w * v.w;
    #pragma unroll
    for (int off = 1; off < 64; off <<= 1) {
        s  += __shfl_xor(s,  off);
        sq += __shfl_xor(sq, off);
    }
    float mu  = s * (1.f / CH);
    float var = sq * (1.f / CH) - mu * mu;
    float rs  = rsqrtf(var + 1e-5f);
    float4 gv = *(const float4*)(g + lane * 4);
    float4 bv = *(const float4*)(b + lane * 4);
    ushort4 ov;
    ov.x = f2bf((v.x - mu) * rs * gv.x + bv.x);
    ov.y = f2bf((v.y - mu) * rs * gv.y + bv.y);
    ov.z = f2bf((v.z - mu) * rs * gv.z + bv.z);
    ov.w = f2bf((v.w - mu) * rs * gv.w + bv.w);
    *(ushort4*)(o + (size_t)row * CH + lane * 4) = ov;
}

// ---------------------------------------------------------------------------
// k_qin: q_in[n][c] = bf16( ln_x[qidx[n]][c] + relu(coords[n]@w_pos + b_pos) )
// ---------------------------------------------------------------------------
__global__ __launch_bounds__(256) void k_qin(const unsigned short* __restrict__ ln_x,
                                             const float* __restrict__ coords,
                                             const int* __restrict__ qidx,
                                             const float* __restrict__ w_pos,
                                             const float* __restrict__ b_pos,
                                             unsigned short* __restrict__ qin) {
    int c = threadIdx.x;
    int nb = blockIdx.x * 8;
    float wp0 = w_pos[c], wp1 = w_pos[CH + c], wp2 = w_pos[2 * CH + c], bp = b_pos[c];
    #pragma unroll
    for (int qq = 0; qq < 8; qq++) {
        int n = nb + qq;
        float p = bp + coords[n * 3] * wp0 + coords[n * 3 + 1] * wp1 + coords[n * 3 + 2] * wp2;
        p = fmaxf(p, 0.f);
        int qi = qidx[n];
        qin[(size_t)n * CH + c] = f2bf(bf2f(ln_x[(size_t)qi * CH + c]) + p);
    }
}

// ---------------------------------------------------------------------------
// k_kv v2: dense kv projection, A-RESIDENT. One block per 128-row tile;
// full A tile (8 chunks x 8 KB = 64 KB) staged once via glds16, then 4
// col-tiles of 128 computed in-block (B staged 8 KB per k-chunk, L2-hit).
// A is fetched from HBM exactly once (was 2x). Untouched voxels (never
// gathered unmasked): staging repointed to rowbase, stores skipped.
// Epilogue per col-tile: LDS transpose (reusing Bs) -> coalesced 16B stores.
// ---------------------------------------------------------------------------
__global__ __launch_bounds__(256) void k_kv(const unsigned short* __restrict__ ln_x,
                                            const unsigned short* __restrict__ w_kv_t,
                                            const float* __restrict__ bkv,
                                            const unsigned char* __restrict__ touched,
                                            unsigned short* __restrict__ kv) {
    __shared__ __align__(16) unsigned short As[8 * 4096];   // 64 KB: 8 chunks x [128][32]
    __shared__ __align__(16) unsigned short Bs[4096];        // 8 KB:  [128][32]
    const int tid = threadIdx.x;
    const int w = tid >> 6, l = tid & 63;
    const int wr = w >> 1, wc = w & 1;
    const int rowbase = blockIdx.x * 128;
    const int sr = l >> 2, sq = l & 3;
    const int ml = l & 15, qd = l >> 4;

    int ra0 = rowbase + w * 16 + sr;
    int ra1 = rowbase + 64 + w * 16 + sr;
    int ok0 = (ra0 < MV) && touched[ra0 < MV ? ra0 : 0];
    int ok1 = (ra1 < MV) && touched[ra1 < MV ? ra1 : 0];
    const unsigned short* pa0 = ln_x + (size_t)(ok0 ? ra0 : rowbase) * CH + sq * 8;
    const unsigned short* pa1 = ln_x + (size_t)(ok1 ? ra1 : rowbase) * CH + sq * 8;
    unsigned short* lA0 = As + w * 512;
    unsigned short* lA1 = As + 2048 + w * 512;
    unsigned short* lB0 = Bs + w * 512;
    unsigned short* lB1 = Bs + 2048 + w * 512;

    #pragma unroll
    for (int c = 0; c < 8; c++) {                   // stage entire A tile once
        glds16(pa0 + c * 32, lA0 + c * 4096);
        glds16(pa1 + c * 32, lA1 + c * 4096);
    }

    for (int ct = 0; ct < 4; ct++) {
        const int col0 = ct * 128;
        const unsigned short* pb0 = w_kv_t + (size_t)(col0 + w * 16 + sr) * CH + sq * 8;
        const unsigned short* pb1 = w_kv_t + (size_t)(col0 + 64 + w * 16 + sr) * CH + sq * 8;
        f32x4 acc[4][4];
        #pragma unroll
        for (int mt = 0; mt < 4; mt++)
            #pragma unroll
            for (int nt = 0; nt < 4; nt++)
                acc[mt][nt] = (f32x4){0.f, 0.f, 0.f, 0.f};

        for (int c = 0; c < 8; c++) {
            __syncthreads();                        // Bs free (prev chunk / transpose)
            glds16(pb0 + c * 32, lB0);
            glds16(pb1 + c * 32, lB1);
            __syncthreads();                        // drains vmcnt (A too on c==0,ct==0)
            bf16x8 af[4], bf[4];
            const unsigned short* Ac = As + c * 4096;
            #pragma unroll
            for (int mt = 0; mt < 4; mt++)
                af[mt] = *(const bf16x8*)(Ac + (wr * 64 + mt * 16 + ml) * 32 + qd * 8);
            #pragma unroll
            for (int nt = 0; nt < 4; nt++)
                bf[nt] = *(const bf16x8*)(Bs + (wc * 64 + nt * 16 + ml) * 32 + qd * 8);
            #pragma unroll
            for (int mt = 0; mt < 4; mt++)
                #pragma unroll
                for (int nt = 0; nt < 4; nt++)
                    acc[mt][nt] = __builtin_amdgcn_mfma_f32_16x16x32_bf16(af[mt], bf[nt], acc[mt][nt], 0, 0, 0);
        }

        // epilogue: bias + LDS transpose (2 bands of 16x128 in Bs) + stores
        float bb[4];
        #pragma unroll
        for (int nt = 0; nt < 4; nt++)
            bb[nt] = bkv[col0 + wc * 64 + nt * 16 + ml];
        #pragma unroll
        for (int mt = 0; mt < 4; mt++) {
            __syncthreads();                        // Bs reads of prev pass done
            #pragma unroll
            for (int nt = 0; nt < 4; nt++) {
                int lcol = wc * 64 + nt * 16 + ml;
                #pragma unroll
                for (int i = 0; i < 4; i++)
                    Bs[wr * 2048 + (qd * 4 + i) * 128 + lcol] = f2bf(acc[mt][nt][i] + bb[nt]);
            }
            __syncthreads();
            int rl = tid >> 4, cc = (tid & 15) * 8;
            int g0 = rowbase + mt * 16 + rl;
            int g1 = rowbase + 64 + mt * 16 + rl;
            if (g0 < MV && touched[g0])
                *(uint4*)(kv + (size_t)g0 * 512 + col0 + cc) = *(const uint4*)(Bs + rl * 128 + cc);
            if (g1 < MV && touched[g1])
                *(uint4*)(kv + (size_t)g1 * 512 + col0 + cc) = *(const uint4*)(Bs + 2048 + rl * 128 + cc);
        }
    }
}

// ---------------------------------------------------------------------------
// k_mm<KD,EPI,LDO>: row GEMM, A[8192][KD] bf16 @ Bt[cols][KD] bf16.
//   EPI 0: relu -> bf16 at ld LDO            (FF1)
//   EPI 1: +bias+res -> fp32 at ld CH        (FF2)
//   EPI 2: +bias+res[qidx[row]] -> fp32      (proj)
//   EPI 3: +bias -> fp32 AND bf16 at ld CH   (q projection)
//   EPI 4: +bias -> fp32 at ld LDO           (qp tables)
// ---------------------------------------------------------------------------
template <int KD, int EPI, int LDO>
__global__ __launch_bounds__(256) void k_mm(const unsigned short* __restrict__ A,
                                            const unsigned short* __restrict__ Bt_g,
                                            const float* __restrict__ bias,
                                            const float* __restrict__ res,
                                            const int* __restrict__ qidx,
                                            unsigned short* __restrict__ out_bf,
                                            float* __restrict__ out_f) {
    __shared__ __align__(16) unsigned short As[128 * ASTR];
    __shared__ __align__(16) unsigned short Bs[64 * ASTR];
    int tid = threadIdx.x;
    int w = tid >> 6, l = tid & 63;
    int rowbase = blockIdx.y * 128;
    int col0 = blockIdx.x * 64;
    int r0 = tid >> 2, qt = tid & 3;
    const unsigned short* a0p = A + (size_t)(rowbase + r0) * KD + qt * 8;
    const unsigned short* a1p = A + (size_t)(rowbase + 64 + r0) * KD + qt * 8;

    f32x4 acc[2][4];
    #pragma unroll
    for (int mt = 0; mt < 2; mt++)
        #pragma unroll
        for (int nt = 0; nt < 4; nt++)
            acc[mt][nt] = (f32x4){0.f, 0.f, 0.f, 0.f};

    const int ml = l & 15, qd = l >> 4;
    for (int kk = 0; kk < KD; kk += 32) {
        __syncthreads();
        uint4 v0 = *(const uint4*)(a0p + kk);
        uint4 v1 = *(const uint4*)(a1p + kk);
        *(uint4*)(As + r0 * ASTR + qt * 8)        = v0;
        *(uint4*)(As + (64 + r0) * ASTR + qt * 8) = v1;
        {
            uint4 bv = *(const uint4*)(Bt_g + (size_t)(col0 + r0) * KD + kk + qt * 8);
            *(uint4*)(Bs + r0 * ASTR + qt * 8) = bv;
        }
        __syncthreads();
        bf16x8 a0 = *(const bf16x8*)(As + (w * 32 + ml) * ASTR + qd * 8);
        bf16x8 a1 = *(const bf16x8*)(As + (w * 32 + 16 + ml) * ASTR + qd * 8);
        #pragma unroll
        for (int nt = 0; nt < 4; nt++) {
            bf16x8 bb = *(const bf16x8*)(Bs + (nt * 16 + ml) * ASTR + qd * 8);
            acc[0][nt] = __builtin_amdgcn_mfma_f32_16x16x32_bf16(a0, bb, acc[0][nt], 0, 0, 0);
            acc[1][nt] = __builtin_amdgcn_mfma_f32_16x16x32_bf16(a1, bb, acc[1][nt], 0, 0, 0);
        }
    }

    #pragma unroll
    for (int nt = 0; nt < 4; nt++) {
        int col = col0 + nt * 16 + ml;
        float bv = bias[col];
        #pragma unroll
        for (int mt = 0; mt < 2; mt++) {
            int rl = w * 32 + mt * 16 + qd * 4;
            #pragma unroll
            for (int i = 0; i < 4; i++) {
                int row = rowbase + rl + i;
                float v = acc[mt][nt][i] + bv;
                if (EPI == 0) {
                    out_bf[(size_t)row * LDO + col] = f2bf(fmaxf(v, 0.f));
                } else if (EPI == 1) {
                    out_f[(size_t)row * CH + col] = v + res[(size_t)row * CH + col];
                } else if (EPI == 2) {
                    int qi = qidx[row];
                    out_f[(size_t)row * CH + col] = v + res[(size_t)qi * CH + col];
                } else if (EPI == 3) {
                    out_f[(size_t)row * CH + col] = v;
                    out_bf[(size_t)row * CH + col] = f2bf(v);
                } else {
                    out_f[(size_t)row * LDO + col] = v;
                }
            }
        }
    }
}

// ---------------------------------------------------------------------------
// k_attn2: FUSED attention. Part 1 (thread=(h,k), 4 queries): logits =
// q.k*DH^-0.5 + qp gathers + dot(k, comb-row); mask -> e=0; softmax -> LDS.
// Part 2 (wave=query): attnln[n][c] = bf16( sum_k attn*v[gidx[n,k]][c] );
// all-masked queries emit b_v. No global attn round-trip.
// ---------------------------------------------------------------------------
__global__ __launch_bounds__(256) void k_attn2(const float* __restrict__ qbuf,
                                               const float* __restrict__ qp,
                                               const unsigned short* __restrict__ kvmat,
                                               const int* __restrict__ gidx,
                                               const int* __restrict__ mask_i,
                                               const int* __restrict__ rel_x,
                                               const int* __restrict__ rel_y,
                                               const int* __restrict__ rel_z,
                                               const float* __restrict__ comb,
                                               const float* __restrict__ b_v,
                                               unsigned short* __restrict__ attnln) {
    __shared__ float q_s[1024];
    __shared__ float qp_s[4 * QPL];
    __shared__ float attn_s[4 * 256];
    __shared__ int mask_s[4 * 32];
    int tid = threadIdx.x;
    int qb = blockIdx.x * 4;
    for (int i = tid; i < 1024; i += 256) q_s[i] = qbuf[(size_t)qb * CH + i];
    for (int i = tid; i < 4 * QPL; i += 256) qp_s[i] = qp[(size_t)qb * QPL + i];
    if (tid < 128) mask_s[tid] = mask_i[qb * 32 + tid];
    __syncthreads();
    int h = tid >> 5, k = tid & 31;
    const float scale = 0.17677669529663687f;   // 32^-0.5
    for (int qq = 0; qq < 4; qq++) {
        int n = qb + qq;
        int gi = n * KN + k;
        int mk = mask_s[qq * 32 + k];
        float lg = -1e9f;
        if (!mk) {
            int rx = rel_x[gi], ry = rel_y[gi], rz = rel_z[gi];
            int g = gidx[gi];
            const uint4* kp = (const uint4*)(kvmat + (size_t)g * 512 + h * DHD);
            float kv[32];
            #pragma unroll
            for (int j = 0; j < 4; j++) {
                uint4 u = kp[j];
                kv[j * 8 + 0] = bf2f((unsigned short)(u.x & 0xFFFF));
                kv[j * 8 + 1] = bf2f((unsigned short)(u.x >> 16));
                kv[j * 8 + 2] = bf2f((unsigned short)(u.y & 0xFFFF));
                kv[j * 8 + 3] = bf2f((unsigned short)(u.y >> 16));
                kv[j * 8 + 4] = bf2f((unsigned short)(u.z & 0xFFFF));
                kv[j * 8 + 5] = bf2f((unsigned short)(u.z >> 16));
                kv[j * 8 + 6] = bf2f((unsigned short)(u.w & 0xFFFF));
                kv[j * 8 + 7] = bf2f((unsigned short)(u.w >> 16));
            }
            const float* cp = comb + ((((h * 15 + rx) * 15 + ry) * 7 + rz) << 5);
            float s1 = 0.f, s2 = 0.f;
            const float* qrow = q_s + qq * CH + h * DHD;
            #pragma unroll
            for (int d = 0; d < 32; d++) {
                s1 += kv[d] * qrow[d];
                s2 += kv[d] * cp[d];
            }
            lg = s1 * scale + s2
               + qp_s[qq * QPL + h * QPW + rx]
               + qp_s[qq * QPL + h * QPW + 15 + ry]
               + qp_s[qq * QPL + h * QPW + 30 + rz];
        }
        float mx = lg;
        #pragma unroll
        for (int off = 1; off <= 16; off <<= 1) mx = fmaxf(mx, __shfl_xor(mx, off));
        float e = mk ? 0.f : __expf(lg - mx);
        float sm = e;
        #pragma unroll
        for (int off = 1; off <= 16; off <<= 1) sm += __shfl_xor(sm, off);
        attn_s[qq * 256 + tid] = (sm > 0.f) ? e / sm : 0.f;
    }
    __syncthreads();

    // part 2: weighted v gather. wave w = query qb + w; lane covers 4 cols.
    int w = tid >> 6, l = tid & 63;
    int n = qb + w;
    int hh = l >> 3;                        // (l*4)>>5
    float a0 = 0.f, a1 = 0.f, a2 = 0.f, a3 = 0.f;
    int nm = 0;
    for (int kk = 0; kk < KN; kk++) {
        if (mask_s[w * 32 + kk]) continue;  // wave-uniform branch
        nm++;
        int g = gidx[n * 32 + kk];
        ushort4 v4 = *(const ushort4*)(kvmat + (size_t)g * 512 + 256 + l * 4);
        float av = attn_s[w * 256 + hh * 32 + kk];
        a0 += av * bf2f(v4.x);
        a1 += av * bf2f(v4.y);
        a2 += av * bf2f(v4.z);
        a3 += av * bf2f(v4.w);
    }
    int col = l * 4;
    if (nm == 0) {
        a0 = b_v[col]; a1 = b_v[col + 1]; a2 = b_v[col + 2]; a3 = b_v[col + 3];
    }
    ushort4 o;
    o.x = f2bf(a0); o.y = f2bf(a1); o.z = f2bf(a2); o.w = f2bf(a3);
    *(ushort4*)(attnln + (size_t)n * CH + col) = o;
}

// ---------------------------------------------------------------------------
extern "C" void kernel_launch(void* const* d_in, const int* in_sizes, int n_in,
                              void* d_out, int out_size, void* d_ws, size_t ws_size,
                              hipStream_t stream) {
    (void)in_sizes; (void)n_in; (void)out_size; (void)ws_size;
    const float* vox    = (const float*)d_in[0];
    const float* coords = (const float*)d_in[1];
    const int*   qidx   = (const int*)d_in[2];
    const int*   gidx   = (const int*)d_in[3];
    const void*  mraw   = d_in[4];
    const int*   rel_x  = (const int*)d_in[5];
    const int*   rel_y  = (const int*)d_in[6];
    const int*   rel_z  = (const int*)d_in[7];
    const float* w_pos  = (const float*)d_in[8];
    const float* b_pos  = (const float*)d_in[9];
    const float* w_q    = (const float*)d_in[10];
    const float* b_q    = (const float*)d_in[11];
    const float* w_k    = (const float*)d_in[12];
    const float* b_k    = (const float*)d_in[13];
    const float* w_v    = (const float*)d_in[14];
    const float* b_v    = (const float*)d_in[15];
    const float* w_proj = (const float*)d_in[16];
    const float* b_proj = (const float*)d_in[17];
    const float* ln1_g  = (const float*)d_in[18];
    const float* ln1_b  = (const float*)d_in[19];
    const float* ln2_g  = (const float*)d_in[20];
    const float* ln2_b  = (const float*)d_in[21];
    const float* w_ff1  = (const float*)d_in[22];
    const float* b_ff1  = (const float*)d_in[23];
    const float* w_ff2  = (const float*)d_in[24];
    const float* b_ff2  = (const float*)d_in[25];
    const float* pos_qx = (const float*)d_in[26];
    const float* pos_qy = (const float*)d_in[27];
    const float* pos_qz = (const float*)d_in[28];
    const float* pos_kx = (const float*)d_in[29];
    const float* pos_ky = (const float*)d_in[30];
    const float* pos_kz = (const float*)d_in[31];

    // workspace carve (~205 MB total)
    char* p = (char*)d_ws;
    auto take = [&](size_t n) { char* r = p; p += (n + 255) & ~(size_t)255; return r; };
    unsigned short* ln_x    = (unsigned short*)take((size_t)MV * CH * 2);   // 51.2 MB
    unsigned short* w_kv_t  = (unsigned short*)take((size_t)512 * 256 * 2);
    unsigned short* w1_t    = (unsigned short*)take((size_t)512 * 256 * 2);
    unsigned short* w2_t    = (unsigned short*)take((size_t)256 * 512 * 2);
    unsigned short* wp_t    = (unsigned short*)take((size_t)256 * 256 * 2);
    unsigned short* wq_t    = (unsigned short*)take((size_t)256 * 256 * 2);
    unsigned short* wqp_t   = (unsigned short*)take((size_t)QPL * 256 * 2);
    float*          bkv     = (float*)take(512 * 4);
    float*          zbias   = (float*)take(QPL * 4);
    int*            flags   = (int*)take(64 * 4);
    int*            mask_i  = (int*)take((size_t)NG * 4);                   // 1.05 MB
    unsigned char*  touched = (unsigned char*)take(MV);                     // 0.1 MB
    float*          comb    = (float*)take((size_t)8 * 15 * 15 * 7 * 32 * 4); // 1.6 MB
    unsigned short* qin     = (unsigned short*)take((size_t)NQ * CH * 2);   // 4.2 MB
    float*          qbuf    = (float*)take((size_t)NQ * CH * 4);            // 8.4 MB
    unsigned short* qbf     = (unsigned short*)take((size_t)NQ * CH * 2);   // 4.2 MB
    float*          qp      = (float*)take((size_t)NQ * QPL * 4);           // 10.5 MB
    unsigned short* kvmat   = (unsigned short*)take((size_t)MV * 512 * 2);  // 102.4 MB
    unsigned short* attnln  = (unsigned short*)take((size_t)NQ * CH * 2);   // 4.2 MB
    float*          actbuf  = (float*)take((size_t)NQ * CH * 4);            // 8.4 MB
    unsigned short* actln   = (unsigned short*)take((size_t)NQ * CH * 2);   // 4.2 MB
    unsigned short* hbuf    = (unsigned short*)take((size_t)NQ * FFD * 2);  // 8.4 MB

    hipMemsetAsync(touched, 0, MV, stream);
    hipLaunchKernelGGL(k_detect_mask, dim3(64), dim3(256), 0, stream,
                       (const unsigned char*)mraw, flags);
    hipLaunchKernelGGL(k_prep, dim3(NG / 256), dim3(256), 0, stream,
                       w_k, w_v, w_ff1, w_ff2, w_proj, w_q, b_k, b_v,
                       pos_qx, pos_qy, pos_qz, mraw, gidx, flags,
                       w_kv_t, w1_t, w2_t, wp_t, wq_t, wqp_t, bkv, zbias,
                       mask_i, touched);
    hipLaunchKernelGGL(k_posc, dim3((8 * 15 * 15 * 7 * 32 + 255) / 256), dim3(256), 0, stream,
                       pos_kx, pos_ky, pos_kz, comb);
    hipLaunchKernelGGL(k_ln, dim3(MV / 4 + 1), dim3(256), 0, stream,
                       vox, ln1_g, ln1_b, ln_x, MV);
    hipLaunchKernelGGL(k_qin, dim3(NQ / 8), dim3(256), 0, stream,
                       ln_x, coords, qidx, w_pos, b_pos, qin);
    // dense kv projection: kv[m][512] = ln_x @ [w_k|w_v] + [b_k|b_v]
    hipLaunchKernelGGL(k_kv, dim3((MV + 127) / 128), dim3(256), 0, stream,
                       ln_x, w_kv_t, bkv, touched, kvmat);
    // q = qin @ wq_t + b_q  (fp32 + bf16)
    hipLaunchKernelGGL(HIP_KERNEL_NAME(k_mm<256, 3, CH>), dim3(4, NQ / 128), dim3(256), 0, stream,
                       qin, wq_t, b_q, (const float*)nullptr, (const int*)nullptr,
                       qbf, qbuf);
    // qp = qbf @ wqp_t  (fp32, ld QPL)
    hipLaunchKernelGGL(HIP_KERNEL_NAME(k_mm<256, 4, QPL>), dim3(QPL / 64, NQ / 128), dim3(256), 0, stream,
                       qbf, wqp_t, zbias, (const float*)nullptr, (const int*)nullptr,
                       (unsigned short*)nullptr, qp);
    // fused attention: logits+softmax+weighted-v
    hipLaunchKernelGGL(k_attn2, dim3(NQ / 4), dim3(256), 0, stream,
                       qbuf, qp, kvmat, gidx, mask_i, rel_x, rel_y, rel_z,
                       comb, b_v, attnln);
    // proj: act = attn_bf16 @ wp_t + b_proj + vox[qidx]
    hipLaunchKernelGGL(HIP_KERNEL_NAME(k_mm<256, 2, CH>), dim3(4, NQ / 128), dim3(256), 0, stream,
                       attnln, wp_t, b_proj, vox, qidx,
                       (unsigned short*)nullptr, actbuf);
    hipLaunchKernelGGL(k_ln, dim3(NQ / 4), dim3(256), 0, stream,
                       actbuf, ln2_g, ln2_b, actln, NQ);
    // FF1: h = relu(actln @ w1_t + b_ff1)
    hipLaunchKernelGGL(HIP_KERNEL_NAME(k_mm<256, 0, FFD>), dim3(8, NQ / 128), dim3(256), 0, stream,
                       actln, w1_t, b_ff1, (const float*)nullptr, (const int*)nullptr,
                       hbuf, (float*)nullptr);
    // FF2: out = h @ w2_t + b_ff2 + act
    hipLaunchKernelGGL(HIP_KERNEL_NAME(k_mm<512, 1, CH>), dim3(4, NQ / 128), dim3(256), 0, stream,
                       hbuf, w2_t, b_ff2, actbuf, (const int*)nullptr,
                       (unsigned short*)nullptr, (float*)d_out);
}

// Round 9
// 401.805 us; speedup vs baseline: 1.0373x; 1.0373x over previous
//
#include <hip/hip_runtime.h>
#include <hip/hip_bf16.h>
#include <math.h>

// Problem constants (fixed by the reference)
#define MV   100000          // voxels
#define NQ   8192            // queries
#define KN   32              // neighbors per query
#define CH   256             // channels
#define NH   8               // heads
#define DHD  32              // head dim
#define FFD  512             // FF hidden
#define NG   (NQ*KN)         // 262144 gathered rows
#define QPW  37              // 15+15+7 rel-pos columns per head (q-side)
#define QPN  (NH*QPW)        // 296
#define QPL  320             // padded qp row stride (multiple of 64)
#define ASTR 40              // padded LDS stride for k_mm
#define KSTR 264             // attn LDS row stride in shorts (528 B -> 4-way banks)

typedef __bf16 bf16x8 __attribute__((ext_vector_type(8)));
typedef float  f32x4  __attribute__((ext_vector_type(4)));

__device__ __forceinline__ float bf2f(unsigned short u) {
    return __uint_as_float(((unsigned int)u) << 16);
}
__device__ __forceinline__ unsigned short f2bf(float f) {
    unsigned int x = __float_as_uint(f);
    unsigned int r = x + 0x7FFFu + ((x >> 16) & 1u);   // RNE
    return (unsigned short)(r >> 16);
}
// async global->LDS, 16 B per lane; LDS dest = wave-uniform base + lane*16
__device__ __forceinline__ void glds16(const unsigned short* g, unsigned short* l) {
    __builtin_amdgcn_global_load_lds(
        (const __attribute__((address_space(1))) void*)g,
        (__attribute__((address_space(3))) void*)l, 16, 0, 0);
}

// ---------------------------------------------------------------------------
// k_detect_mask: gather_mask may ship as int32 (0/1) or raw 1-byte bools.
// ---------------------------------------------------------------------------
__global__ __launch_bounds__(256) void k_detect_mask(const unsigned char* __restrict__ raw,
                                                     int* __restrict__ flags) {
    __shared__ int any;
    if (threadIdx.x == 0) any = 0;
    __syncthreads();
    const uint4* p = (const uint4*)raw;             // NG bytes = 16384 uint4
    int i = blockIdx.x * 256 + threadIdx.x;
    uint4 v = p[i];
    if ((v.x | v.y | v.z | v.w) & 0xFFFFFF00u) any = 1;
    __syncthreads();
    if (threadIdx.x == 0) flags[blockIdx.x] = any;
}

// ---------------------------------------------------------------------------
// k_prep: int mask (layout-adaptive) + touched-voxel map + bf16 col-major
// (B-layout) weights + bkv = [b_k|b_v] + zbias.
// touched[] must be zeroed before this kernel (hipMemsetAsync).
// ---------------------------------------------------------------------------
__global__ __launch_bounds__(256) void k_prep(const float* __restrict__ w_k,
                                              const float* __restrict__ w_v,
                                              const float* __restrict__ w_ff1,
                                              const float* __restrict__ w_ff2,
                                              const float* __restrict__ w_proj,
                                              const float* __restrict__ w_q,
                                              const float* __restrict__ b_k,
                                              const float* __restrict__ b_v,
                                              const float* __restrict__ pos_qx,
                                              const float* __restrict__ pos_qy,
                                              const float* __restrict__ pos_qz,
                                              const void* __restrict__ mask_raw,
                                              const int* __restrict__ gidx,
                                              const int* __restrict__ flags,
                                              unsigned short* __restrict__ w_kv_t,
                                              unsigned short* __restrict__ w1_t,
                                              unsigned short* __restrict__ w2_t,
                                              unsigned short* __restrict__ wp_t,
                                              unsigned short* __restrict__ wq_t,
                                              unsigned short* __restrict__ wqp_t,
                                              float* __restrict__ bkv,
                                              float* __restrict__ zbias,
                                              int* __restrict__ mask_i,
                                              unsigned char* __restrict__ touched) {
    __shared__ int bl;
    if (threadIdx.x == 0) {
        int a = 0;
        #pragma unroll 8
        for (int i = 0; i < 64; i++) a |= flags[i];
        bl = a;
    }
    __syncthreads();
    int byteLayout = bl;
    int idx = blockIdx.x * 256 + threadIdx.x;       // grid 1024 -> 262144
    if (blockIdx.x == 0 && threadIdx.x < 512)
        bkv[threadIdx.x] = (threadIdx.x < 256) ? b_k[threadIdx.x]
                                               : b_v[threadIdx.x - 256];
    if (idx < QPL) zbias[idx] = 0.f;
    if (idx < NG) {
        int mv = byteLayout ? (int)((const unsigned char*)mask_raw)[idx]
                            : ((const int*)mask_raw)[idx];
        mask_i[idx] = (mv != 0) ? 1 : 0;
        if (mv == 0) touched[gidx[idx]] = 1;        // idempotent byte store
    }
    if (idx < 512 * 256) {
        int col = idx >> 8, j = idx & 255;
        float v = (col < 256) ? w_k[j * 256 + col] : w_v[j * 256 + (col - 256)];
        w_kv_t[idx] = f2bf(v);
    }
    if (idx < 512 * 256) {
        int n = idx >> 8, k = idx & 255;
        w1_t[idx] = f2bf(w_ff1[k * FFD + n]);
    }
    if (idx < 256 * 512) {
        int n = idx >> 9, k = idx & 511;
        w2_t[idx] = f2bf(w_ff2[k * CH + n]);
    }
    if (idx < 256 * 256) {
        int n = idx >> 8, k = idx & 255;
        wp_t[idx] = f2bf(w_proj[k * CH + n]);
        wq_t[idx] = f2bf(w_q[k * CH + n]);
    }
    if (idx < QPL * 256) {                          // wqp_t[col][k]
        int col = idx >> 8, k = idx & 255;
        float v = 0.f;
        if (col < QPN) {
            int h = col / QPW, r = col % QPW;
            int h2 = k >> 5, d = k & 31;
            if (h2 == h) {
                if (r < 15)      v = pos_qx[(h * DHD + d) * 15 + r];
                else if (r < 30) v = pos_qy[(h * DHD + d) * 15 + (r - 15)];
                else             v = pos_qz[(h * DHD + d) * 7  + (r - 30)];
            }
        }
        wqp_t[idx] = f2bf(v);
    }
}

// ---------------------------------------------------------------------------
// k_posc: comb[h][rx][ry][rz][d] = pos_kx[h][d][rx]+pos_ky[h][d][ry]+pos_kz[h][d][rz]
// ---------------------------------------------------------------------------
__global__ __launch_bounds__(256) void k_posc(const float* __restrict__ pos_kx,
                                              const float* __restrict__ pos_ky,
                                              const float* __restrict__ pos_kz,
                                              float* __restrict__ comb) {
    int idx = blockIdx.x * 256 + threadIdx.x;
    if (idx >= 8 * 15 * 15 * 7 * 32) return;
    int d = idx & 31, r = idx >> 5;
    int rz = r % 7;  r /= 7;
    int ry = r % 15; r /= 15;
    int rx = r % 15; int h = r / 15;
    comb[idx] = pos_kx[(h * DHD + d) * 15 + rx]
              + pos_ky[(h * DHD + d) * 15 + ry]
              + pos_kz[(h * DHD + d) * 7  + rz];
}

// ---------------------------------------------------------------------------
// k_ln: LayerNorm rows of x[nrows][256] -> bf16. One wave per row.
// ---------------------------------------------------------------------------
__global__ __launch_bounds__(256) void k_ln(const float* __restrict__ x,
                                            const float* __restrict__ g,
                                            const float* __restrict__ b,
                                            unsigned short* __restrict__ o,
                                            int nrows) {
    int wid = threadIdx.x >> 6, lane = threadIdx.x & 63;
    int row = blockIdx.x * 4 + wid;
    if (row >= nrows) return;
    const float4 v = *(const float4*)(x + (size_t)row * CH + lane * 4);
    float s  = v.x + v.y + v.z + v.w;
    float sq = v.x * v.x + v.y * v.y + v.z * v.z + v.w * v.w;
    #pragma unroll
    for (int off = 1; off < 64; off <<= 1) {
        s  += __shfl_xor(s,  off);
        sq += __shfl_xor(sq, off);
    }
    float mu  = s * (1.f / CH);
    float var = sq * (1.f / CH) - mu * mu;
    float rs  = rsqrtf(var + 1e-5f);
    float4 gv = *(const float4*)(g + lane * 4);
    float4 bv = *(const float4*)(b + lane * 4);
    ushort4 ov;
    ov.x = f2bf((v.x - mu) * rs * gv.x + bv.x);
    ov.y = f2bf((v.y - mu) * rs * gv.y + bv.y);
    ov.z = f2bf((v.z - mu) * rs * gv.z + bv.z);
    ov.w = f2bf((v.w - mu) * rs * gv.w + bv.w);
    *(ushort4*)(o + (size_t)row * CH + lane * 4) = ov;
}

// ---------------------------------------------------------------------------
// k_qin: q_in[n][c] = bf16( ln_x[qidx[n]][c] + relu(coords[n]@w_pos + b_pos) )
// ---------------------------------------------------------------------------
__global__ __launch_bounds__(256) void k_qin(const unsigned short* __restrict__ ln_x,
                                             const float* __restrict__ coords,
                                             const int* __restrict__ qidx,
                                             const float* __restrict__ w_pos,
                                             const float* __restrict__ b_pos,
                                             unsigned short* __restrict__ qin) {
    int c = threadIdx.x;
    int nb = blockIdx.x * 8;
    float wp0 = w_pos[c], wp1 = w_pos[CH + c], wp2 = w_pos[2 * CH + c], bp = b_pos[c];
    #pragma unroll
    for (int qq = 0; qq < 8; qq++) {
        int n = nb + qq;
        float p = bp + coords[n * 3] * wp0 + coords[n * 3 + 1] * wp1 + coords[n * 3 + 2] * wp2;
        p = fmaxf(p, 0.f);
        int qi = qidx[n];
        qin[(size_t)n * CH + c] = f2bf(bf2f(ln_x[(size_t)qi * CH + c]) + p);
    }
}

// ---------------------------------------------------------------------------
// k_kv v2: dense kv projection, A-RESIDENT (unchanged from R8; <=74us, low
// fetch). Untouched voxels pruned on both fetch and store.
// ---------------------------------------------------------------------------
__global__ __launch_bounds__(256) void k_kv(const unsigned short* __restrict__ ln_x,
                                            const unsigned short* __restrict__ w_kv_t,
                                            const float* __restrict__ bkv,
                                            const unsigned char* __restrict__ touched,
                                            unsigned short* __restrict__ kv) {
    __shared__ __align__(16) unsigned short As[8 * 4096];   // 64 KB: 8 chunks x [128][32]
    __shared__ __align__(16) unsigned short Bs[4096];        // 8 KB:  [128][32]
    const int tid = threadIdx.x;
    const int w = tid >> 6, l = tid & 63;
    const int wr = w >> 1, wc = w & 1;
    const int rowbase = blockIdx.x * 128;
    const int sr = l >> 2, sq = l & 3;
    const int ml = l & 15, qd = l >> 4;

    int ra0 = rowbase + w * 16 + sr;
    int ra1 = rowbase + 64 + w * 16 + sr;
    int ok0 = (ra0 < MV) && touched[ra0 < MV ? ra0 : 0];
    int ok1 = (ra1 < MV) && touched[ra1 < MV ? ra1 : 0];
    const unsigned short* pa0 = ln_x + (size_t)(ok0 ? ra0 : rowbase) * CH + sq * 8;
    const unsigned short* pa1 = ln_x + (size_t)(ok1 ? ra1 : rowbase) * CH + sq * 8;
    unsigned short* lA0 = As + w * 512;
    unsigned short* lA1 = As + 2048 + w * 512;
    unsigned short* lB0 = Bs + w * 512;
    unsigned short* lB1 = Bs + 2048 + w * 512;

    #pragma unroll
    for (int c = 0; c < 8; c++) {                   // stage entire A tile once
        glds16(pa0 + c * 32, lA0 + c * 4096);
        glds16(pa1 + c * 32, lA1 + c * 4096);
    }

    for (int ct = 0; ct < 4; ct++) {
        const int col0 = ct * 128;
        const unsigned short* pb0 = w_kv_t + (size_t)(col0 + w * 16 + sr) * CH + sq * 8;
        const unsigned short* pb1 = w_kv_t + (size_t)(col0 + 64 + w * 16 + sr) * CH + sq * 8;
        f32x4 acc[4][4];
        #pragma unroll
        for (int mt = 0; mt < 4; mt++)
            #pragma unroll
            for (int nt = 0; nt < 4; nt++)
                acc[mt][nt] = (f32x4){0.f, 0.f, 0.f, 0.f};

        for (int c = 0; c < 8; c++) {
            __syncthreads();                        // Bs free (prev chunk / transpose)
            glds16(pb0 + c * 32, lB0);
            glds16(pb1 + c * 32, lB1);
            __syncthreads();                        // drains vmcnt
            bf16x8 af[4], bf[4];
            const unsigned short* Ac = As + c * 4096;
            #pragma unroll
            for (int mt = 0; mt < 4; mt++)
                af[mt] = *(const bf16x8*)(Ac + (wr * 64 + mt * 16 + ml) * 32 + qd * 8);
            #pragma unroll
            for (int nt = 0; nt < 4; nt++)
                bf[nt] = *(const bf16x8*)(Bs + (wc * 64 + nt * 16 + ml) * 32 + qd * 8);
            #pragma unroll
            for (int mt = 0; mt < 4; mt++)
                #pragma unroll
                for (int nt = 0; nt < 4; nt++)
                    acc[mt][nt] = __builtin_amdgcn_mfma_f32_16x16x32_bf16(af[mt], bf[nt], acc[mt][nt], 0, 0, 0);
        }

        // epilogue: bias + LDS transpose (2 bands of 16x128 in Bs) + stores
        float bb[4];
        #pragma unroll
        for (int nt = 0; nt < 4; nt++)
            bb[nt] = bkv[col0 + wc * 64 + nt * 16 + ml];
        #pragma unroll
        for (int mt = 0; mt < 4; mt++) {
            __syncthreads();
            #pragma unroll
            for (int nt = 0; nt < 4; nt++) {
                int lcol = wc * 64 + nt * 16 + ml;
                #pragma unroll
                for (int i = 0; i < 4; i++)
                    Bs[wr * 2048 + (qd * 4 + i) * 128 + lcol] = f2bf(acc[mt][nt][i] + bb[nt]);
            }
            __syncthreads();
            int rl = tid >> 4, cc = (tid & 15) * 8;
            int g0 = rowbase + mt * 16 + rl;
            int g1 = rowbase + 64 + mt * 16 + rl;
            if (g0 < MV && touched[g0])
                *(uint4*)(kv + (size_t)g0 * 512 + col0 + cc) = *(const uint4*)(Bs + rl * 128 + cc);
            if (g1 < MV && touched[g1])
                *(uint4*)(kv + (size_t)g1 * 512 + col0 + cc) = *(const uint4*)(Bs + 2048 + rl * 128 + cc);
        }
    }
}

// ---------------------------------------------------------------------------
// k_mm<KD,EPI,LDO>: row GEMM, A[8192][KD] bf16 @ Bt[cols][KD] bf16.
//   EPI 0: relu -> bf16 at ld LDO            (FF1)
//   EPI 1: +bias+res -> fp32 at ld CH        (FF2)
//   EPI 2: +bias+res[qidx[row]] -> fp32      (proj)
//   EPI 3: +bias -> fp32 AND bf16 at ld CH   (q projection)
//   EPI 4: +bias -> fp32 at ld LDO           (qp tables)
// ---------------------------------------------------------------------------
template <int KD, int EPI, int LDO>
__global__ __launch_bounds__(256) void k_mm(const unsigned short* __restrict__ A,
                                            const unsigned short* __restrict__ Bt_g,
                                            const float* __restrict__ bias,
                                            const float* __restrict__ res,
                                            const int* __restrict__ qidx,
                                            unsigned short* __restrict__ out_bf,
                                            float* __restrict__ out_f) {
    __shared__ __align__(16) unsigned short As[128 * ASTR];
    __shared__ __align__(16) unsigned short Bs[64 * ASTR];
    int tid = threadIdx.x;
    int w = tid >> 6, l = tid & 63;
    int rowbase = blockIdx.y * 128;
    int col0 = blockIdx.x * 64;
    int r0 = tid >> 2, qt = tid & 3;
    const unsigned short* a0p = A + (size_t)(rowbase + r0) * KD + qt * 8;
    const unsigned short* a1p = A + (size_t)(rowbase + 64 + r0) * KD + qt * 8;

    f32x4 acc[2][4];
    #pragma unroll
    for (int mt = 0; mt < 2; mt++)
        #pragma unroll
        for (int nt = 0; nt < 4; nt++)
            acc[mt][nt] = (f32x4){0.f, 0.f, 0.f, 0.f};

    const int ml = l & 15, qd = l >> 4;
    for (int kk = 0; kk < KD; kk += 32) {
        __syncthreads();
        uint4 v0 = *(const uint4*)(a0p + kk);
        uint4 v1 = *(const uint4*)(a1p + kk);
        *(uint4*)(As + r0 * ASTR + qt * 8)        = v0;
        *(uint4*)(As + (64 + r0) * ASTR + qt * 8) = v1;
        {
            uint4 bv = *(const uint4*)(Bt_g + (size_t)(col0 + r0) * KD + kk + qt * 8);
            *(uint4*)(Bs + r0 * ASTR + qt * 8) = bv;
        }
        __syncthreads();
        bf16x8 a0 = *(const bf16x8*)(As + (w * 32 + ml) * ASTR + qd * 8);
        bf16x8 a1 = *(const bf16x8*)(As + (w * 32 + 16 + ml) * ASTR + qd * 8);
        #pragma unroll
        for (int nt = 0; nt < 4; nt++) {
            bf16x8 bb = *(const bf16x8*)(Bs + (nt * 16 + ml) * ASTR + qd * 8);
            acc[0][nt] = __builtin_amdgcn_mfma_f32_16x16x32_bf16(a0, bb, acc[0][nt], 0, 0, 0);
            acc[1][nt] = __builtin_amdgcn_mfma_f32_16x16x32_bf16(a1, bb, acc[1][nt], 0, 0, 0);
        }
    }

    #pragma unroll
    for (int nt = 0; nt < 4; nt++) {
        int col = col0 + nt * 16 + ml;
        float bv = bias[col];
        #pragma unroll
        for (int mt = 0; mt < 2; mt++) {
            int rl = w * 32 + mt * 16 + qd * 4;
            #pragma unroll
            for (int i = 0; i < 4; i++) {
                int row = rowbase + rl + i;
                float v = acc[mt][nt][i] + bv;
                if (EPI == 0) {
                    out_bf[(size_t)row * LDO + col] = f2bf(fmaxf(v, 0.f));
                } else if (EPI == 1) {
                    out_f[(size_t)row * CH + col] = v + res[(size_t)row * CH + col];
                } else if (EPI == 2) {
                    int qi = qidx[row];
                    out_f[(size_t)row * CH + col] = v + res[(size_t)qi * CH + col];
                } else if (EPI == 3) {
                    out_f[(size_t)row * CH + col] = v;
                    out_bf[(size_t)row * CH + col] = f2bf(v);
                } else {
                    out_f[(size_t)row * LDO + col] = v;
                }
            }
        }
    }
}

// ---------------------------------------------------------------------------
// k_attn3: staged-LDS fused attention. 2 queries/block (64 gathered rows).
// Phase A: coalesced restage of k-parts (512 B/row, 16 B/lane, 8 independent
// rounds, masked rows -> zeros) into ks[64][KSTR]. Part 1: logits+softmax
// from LDS. Phase B: restage v-parts into the same buffer. Part 2: wave w =
// (query w>>1, neighbor-half w&1) accumulates attn*v from LDS; halves combine
// via repurposed qp_s; all-masked queries emit b_v.
// ---------------------------------------------------------------------------
__global__ __launch_bounds__(256) void k_attn3(const float* __restrict__ qbuf,
                                               const float* __restrict__ qp,
                                               const unsigned short* __restrict__ kvmat,
                                               const int* __restrict__ gidx,
                                               const int* __restrict__ mask_i,
                                               const int* __restrict__ rel_x,
                                               const int* __restrict__ rel_y,
                                               const int* __restrict__ rel_z,
                                               const float* __restrict__ comb,
                                               const float* __restrict__ b_v,
                                               unsigned short* __restrict__ attnln) {
    __shared__ float q_s[2 * 256];
    __shared__ float qp_s[2 * QPL];                 // reused as partial sums in part 2
    __shared__ float attn_s[2 * 256];
    __shared__ int   mask_s[64];
    __shared__ int   gidx_s[64];
    __shared__ __align__(16) unsigned short ks[64 * KSTR];   // 33 KB

    int tid = threadIdx.x;
    int qb = blockIdx.x * 2;
    for (int i = tid; i < 512; i += 256) q_s[i] = qbuf[(size_t)qb * CH + i];
    for (int i = tid; i < 2 * QPL; i += 256) qp_s[i] = qp[(size_t)qb * QPL + i];
    if (tid < 64) {
        mask_s[tid] = mask_i[qb * 32 + tid];
        gidx_s[tid] = gidx[qb * 32 + tid];
    }
    __syncthreads();

    // ---- Phase A: stage k-parts (rows' first 512 B), coalesced ----
    const int srow = tid >> 5;                      // 0..7
    const int schk = tid & 31;                      // 16 B chunk within row
    uint4 kreg[8];
    #pragma unroll
    for (int j = 0; j < 8; j++) {
        int r = j * 8 + srow;
        uint4 v = {0u, 0u, 0u, 0u};
        if (!mask_s[r])
            v = *(const uint4*)(kvmat + (size_t)gidx_s[r] * 512 + schk * 8);
        kreg[j] = v;
    }
    #pragma unroll
    for (int j = 0; j < 8; j++)
        *(uint4*)(ks + (j * 8 + srow) * KSTR + schk * 8) = kreg[j];
    __syncthreads();

    // ---- Part 1: logits + softmax from LDS ----
    int h = tid >> 5, k = tid & 31;
    const float scale = 0.17677669529663687f;       // 32^-0.5
    for (int qq = 0; qq < 2; qq++) {
        int n = qb + qq;
        int gi = n * KN + k;
        int r = qq * 32 + k;
        int mk = mask_s[r];
        float lg = -1e9f;
        if (!mk) {
            int rx = rel_x[gi], ry = rel_y[gi], rz = rel_z[gi];
            const unsigned short* kp = ks + r * KSTR + h * 32;
            float kv[32];
            #pragma unroll
            for (int j = 0; j < 4; j++) {
                uint4 u = *(const uint4*)(kp + j * 8);
                kv[j * 8 + 0] = bf2f((unsigned short)(u.x & 0xFFFF));
                kv[j * 8 + 1] = bf2f((unsigned short)(u.x >> 16));
                kv[j * 8 + 2] = bf2f((unsigned short)(u.y & 0xFFFF));
                kv[j * 8 + 3] = bf2f((unsigned short)(u.y >> 16));
                kv[j * 8 + 4] = bf2f((unsigned short)(u.z & 0xFFFF));
                kv[j * 8 + 5] = bf2f((unsigned short)(u.z >> 16));
                kv[j * 8 + 6] = bf2f((unsigned short)(u.w & 0xFFFF));
                kv[j * 8 + 7] = bf2f((unsigned short)(u.w >> 16));
            }
            const float* cp = comb + ((((h * 15 + rx) * 15 + ry) * 7 + rz) << 5);
            float s1 = 0.f, s2 = 0.f;
            const float* qrow = q_s + qq * CH + h * DHD;
            #pragma unroll
            for (int d = 0; d < 32; d++) {
                s1 += kv[d] * qrow[d];
                s2 += kv[d] * cp[d];
            }
            lg = s1 * scale + s2
               + qp_s[qq * QPL + h * QPW + rx]
               + qp_s[qq * QPL + h * QPW + 15 + ry]
               + qp_s[qq * QPL + h * QPW + 30 + rz];
        }
        float mx = lg;
        #pragma unroll
        for (int off = 1; off <= 16; off <<= 1) mx = fmaxf(mx, __shfl_xor(mx, off));
        float e = mk ? 0.f : __expf(lg - mx);
        float sm = e;
        #pragma unroll
        for (int off = 1; off <= 16; off <<= 1) sm += __shfl_xor(sm, off);
        attn_s[qq * 256 + tid] = (sm > 0.f) ? e / sm : 0.f;
    }

    // ---- Phase B: restage v-parts into the same buffer ----
    #pragma unroll
    for (int j = 0; j < 8; j++) {
        int r = j * 8 + srow;
        uint4 v = {0u, 0u, 0u, 0u};
        if (!mask_s[r])
            v = *(const uint4*)(kvmat + (size_t)gidx_s[r] * 512 + 256 + schk * 8);
        kreg[j] = v;
    }
    __syncthreads();                                // part-1 ks reads + attn_s writes done
    #pragma unroll
    for (int j = 0; j < 8; j++)
        *(uint4*)(ks + (j * 8 + srow) * KSTR + schk * 8) = kreg[j];
    __syncthreads();

    // ---- Part 2: weighted v from LDS. wave w = (query w>>1, half w&1) ----
    int w = tid >> 6, l = tid & 63;
    int q2 = w >> 1, kh = w & 1;
    int hh = l >> 3;                                // head of col group l*4
    float a0 = 0.f, a1 = 0.f, a2 = 0.f, a3 = 0.f;
    #pragma unroll
    for (int i = 0; i < 16; i++) {
        int kk = kh * 16 + i;
        int r = q2 * 32 + kk;
        float av = attn_s[q2 * 256 + hh * 32 + kk]; // 0 for masked
        ushort4 v4 = *(const ushort4*)(ks + r * KSTR + l * 4);
        a0 += av * bf2f(v4.x);
        a1 += av * bf2f(v4.y);
        a2 += av * bf2f(v4.z);
        a3 += av * bf2f(v4.w);
    }
    if (kh == 1) {
        float4 pv = {a0, a1, a2, a3};
        *(float4*)(qp_s + q2 * 256 + l * 4) = pv;   // qp_s repurposed (>=512 floats)
    }
    __syncthreads();
    if (kh == 0) {
        float4 pv = *(const float4*)(qp_s + q2 * 256 + l * 4);
        a0 += pv.x; a1 += pv.y; a2 += pv.z; a3 += pv.w;
        int nm = 0;
        #pragma unroll
        for (int kk = 0; kk < 32; kk++) nm += 1 - mask_s[q2 * 32 + kk];
        int col = l * 4;
        if (nm == 0) {
            a0 = b_v[col]; a1 = b_v[col + 1]; a2 = b_v[col + 2]; a3 = b_v[col + 3];
        }
        ushort4 o;
        o.x = f2bf(a0); o.y = f2bf(a1); o.z = f2bf(a2); o.w = f2bf(a3);
        *(ushort4*)(attnln + (size_t)(qb + q2) * CH + col) = o;
    }
}

// ---------------------------------------------------------------------------
extern "C" void kernel_launch(void* const* d_in, const int* in_sizes, int n_in,
                              void* d_out, int out_size, void* d_ws, size_t ws_size,
                              hipStream_t stream) {
    (void)in_sizes; (void)n_in; (void)out_size; (void)ws_size;
    const float* vox    = (const float*)d_in[0];
    const float* coords = (const float*)d_in[1];
    const int*   qidx   = (const int*)d_in[2];
    const int*   gidx   = (const int*)d_in[3];
    const void*  mraw   = d_in[4];
    const int*   rel_x  = (const int*)d_in[5];
    const int*   rel_y  = (const int*)d_in[6];
    const int*   rel_z  = (const int*)d_in[7];
    const float* w_pos  = (const float*)d_in[8];
    const float* b_pos  = (const float*)d_in[9];
    const float* w_q    = (const float*)d_in[10];
    const float* b_q    = (const float*)d_in[11];
    const float* w_k    = (const float*)d_in[12];
    const float* b_k    = (const float*)d_in[13];
    const float* w_v    = (const float*)d_in[14];
    const float* b_v    = (const float*)d_in[15];
    const float* w_proj = (const float*)d_in[16];
    const float* b_proj = (const float*)d_in[17];
    const float* ln1_g  = (const float*)d_in[18];
    const float* ln1_b  = (const float*)d_in[19];
    const float* ln2_g  = (const float*)d_in[20];
    const float* ln2_b  = (const float*)d_in[21];
    const float* w_ff1  = (const float*)d_in[22];
    const float* b_ff1  = (const float*)d_in[23];
    const float* w_ff2  = (const float*)d_in[24];
    const float* b_ff2  = (const float*)d_in[25];
    const float* pos_qx = (const float*)d_in[26];
    const float* pos_qy = (const float*)d_in[27];
    const float* pos_qz = (const float*)d_in[28];
    const float* pos_kx = (const float*)d_in[29];
    const float* pos_ky = (const float*)d_in[30];
    const float* pos_kz = (const float*)d_in[31];

    // workspace carve (~205 MB total)
    char* p = (char*)d_ws;
    auto take = [&](size_t n) { char* r = p; p += (n + 255) & ~(size_t)255; return r; };
    unsigned short* ln_x    = (unsigned short*)take((size_t)MV * CH * 2);   // 51.2 MB
    unsigned short* w_kv_t  = (unsigned short*)take((size_t)512 * 256 * 2);
    unsigned short* w1_t    = (unsigned short*)take((size_t)512 * 256 * 2);
    unsigned short* w2_t    = (unsigned short*)take((size_t)256 * 512 * 2);
    unsigned short* wp_t    = (unsigned short*)take((size_t)256 * 256 * 2);
    unsigned short* wq_t    = (unsigned short*)take((size_t)256 * 256 * 2);
    unsigned short* wqp_t   = (unsigned short*)take((size_t)QPL * 256 * 2);
    float*          bkv     = (float*)take(512 * 4);
    float*          zbias   = (float*)take(QPL * 4);
    int*            flags   = (int*)take(64 * 4);
    int*            mask_i  = (int*)take((size_t)NG * 4);                   // 1.05 MB
    unsigned char*  touched = (unsigned char*)take(MV);                     // 0.1 MB
    float*          comb    = (float*)take((size_t)8 * 15 * 15 * 7 * 32 * 4); // 1.6 MB
    unsigned short* qin     = (unsigned short*)take((size_t)NQ * CH * 2);   // 4.2 MB
    float*          qbuf    = (float*)take((size_t)NQ * CH * 4);            // 8.4 MB
    unsigned short* qbf     = (unsigned short*)take((size_t)NQ * CH * 2);   // 4.2 MB
    float*          qp      = (float*)take((size_t)NQ * QPL * 4);           // 10.5 MB
    unsigned short* kvmat   = (unsigned short*)take((size_t)MV * 512 * 2);  // 102.4 MB
    unsigned short* attnln  = (unsigned short*)take((size_t)NQ * CH * 2);   // 4.2 MB
    float*          actbuf  = (float*)take((size_t)NQ * CH * 4);            // 8.4 MB
    unsigned short* actln   = (unsigned short*)take((size_t)NQ * CH * 2);   // 4.2 MB
    unsigned short* hbuf    = (unsigned short*)take((size_t)NQ * FFD * 2);  // 8.4 MB

    hipMemsetAsync(touched, 0, MV, stream);
    hipLaunchKernelGGL(k_detect_mask, dim3(64), dim3(256), 0, stream,
                       (const unsigned char*)mraw, flags);
    hipLaunchKernelGGL(k_prep, dim3(NG / 256), dim3(256), 0, stream,
                       w_k, w_v, w_ff1, w_ff2, w_proj, w_q, b_k, b_v,
                       pos_qx, pos_qy, pos_qz, mraw, gidx, flags,
                       w_kv_t, w1_t, w2_t, wp_t, wq_t, wqp_t, bkv, zbias,
                       mask_i, touched);
    hipLaunchKernelGGL(k_posc, dim3((8 * 15 * 15 * 7 * 32 + 255) / 256), dim3(256), 0, stream,
                       pos_kx, pos_ky, pos_kz, comb);
    hipLaunchKernelGGL(k_ln, dim3(MV / 4 + 1), dim3(256), 0, stream,
                       vox, ln1_g, ln1_b, ln_x, MV);
    hipLaunchKernelGGL(k_qin, dim3(NQ / 8), dim3(256), 0, stream,
                       ln_x, coords, qidx, w_pos, b_pos, qin);
    // dense kv projection: kv[m][512] = ln_x @ [w_k|w_v] + [b_k|b_v]
    hipLaunchKernelGGL(k_kv, dim3((MV + 127) / 128), dim3(256), 0, stream,
                       ln_x, w_kv_t, bkv, touched, kvmat);
    // q = qin @ wq_t + b_q  (fp32 + bf16)
    hipLaunchKernelGGL(HIP_KERNEL_NAME(k_mm<256, 3, CH>), dim3(4, NQ / 128), dim3(256), 0, stream,
                       qin, wq_t, b_q, (const float*)nullptr, (const int*)nullptr,
                       qbf, qbuf);
    // qp = qbf @ wqp_t  (fp32, ld QPL)
    hipLaunchKernelGGL(HIP_KERNEL_NAME(k_mm<256, 4, QPL>), dim3(QPL / 64, NQ / 128), dim3(256), 0, stream,
                       qbf, wqp_t, zbias, (const float*)nullptr, (const int*)nullptr,
                       (unsigned short*)nullptr, qp);
    // staged-LDS fused attention
    hipLaunchKernelGGL(k_attn3, dim3(NQ / 2), dim3(256), 0, stream,
                       qbuf, qp, kvmat, gidx, mask_i, rel_x, rel_y, rel_z,
                       comb, b_v, attnln);
    // proj: act = attn_bf16 @ wp_t + b_proj + vox[qidx]
    hipLaunchKernelGGL(HIP_KERNEL_NAME(k_mm<256, 2, CH>), dim3(4, NQ / 128), dim3(256), 0, stream,
                       attnln, wp_t, b_proj, vox, qidx,
                       (unsigned short*)nullptr, actbuf);
    hipLaunchKernelGGL(k_ln, dim3(NQ / 4), dim3(256), 0, stream,
                       actbuf, ln2_g, ln2_b, actln, NQ);
    // FF1: h = relu(actln @ w1_t + b_ff1)
    hipLaunchKernelGGL(HIP_KERNEL_NAME(k_mm<256, 0, FFD>), dim3(8, NQ / 128), dim3(256), 0, stream,
                       actln, w1_t, b_ff1, (const float*)nullptr, (const int*)nullptr,
                       hbuf, (float*)nullptr);
    // FF2: out = h @ w2_t + b_ff2 + act
    hipLaunchKernelGGL(HIP_KERNEL_NAME(k_mm<512, 1, CH>), dim3(4, NQ / 128), dim3(256), 0, stream,
                       hbuf, w2_t, b_ff2, actbuf, (const int*)nullptr,
                       (unsigned short*)nullptr, (float*)d_out);
}

// Round 10
// 391.056 us; speedup vs baseline: 1.0658x; 1.0275x over previous
//
#include <hip/hip_runtime.h>
#include <hip/hip_bf16.h>
#include <math.h>

// Problem constants (fixed by the reference)
#define MV   100000          // voxels
#define NQ   8192            // queries
#define KN   32              // neighbors per query
#define CH   256             // channels
#define NH   8               // heads
#define DHD  32              // head dim
#define FFD  512             // FF hidden
#define NG   (NQ*KN)         // 262144 gathered rows
#define QPW  37              // 15+15+7 rel-pos columns per head (q-side)
#define QPN  (NH*QPW)        // 296
#define QPL  320             // padded qp row stride (multiple of 64)
#define ASTR 40              // padded LDS stride for k_mm
#define KSTR 264             // attn LDS row stride in shorts (528 B -> 4-way banks)

typedef __bf16 bf16x8 __attribute__((ext_vector_type(8)));
typedef float  f32x4  __attribute__((ext_vector_type(4)));

__device__ __forceinline__ float bf2f(unsigned short u) {
    return __uint_as_float(((unsigned int)u) << 16);
}
__device__ __forceinline__ unsigned short f2bf(float f) {
    unsigned int x = __float_as_uint(f);
    unsigned int r = x + 0x7FFFu + ((x >> 16) & 1u);   // RNE
    return (unsigned short)(r >> 16);
}
// async global->LDS, 16 B per lane; LDS dest = wave-uniform base + lane*16
__device__ __forceinline__ void glds16(const unsigned short* g, unsigned short* l) {
    __builtin_amdgcn_global_load_lds(
        (const __attribute__((address_space(1))) void*)g,
        (__attribute__((address_space(3))) void*)l, 16, 0, 0);
}

// ---------------------------------------------------------------------------
// k_detect_mask: gather_mask may ship as int32 (0/1) or raw 1-byte bools.
// ---------------------------------------------------------------------------
__global__ __launch_bounds__(256) void k_detect_mask(const unsigned char* __restrict__ raw,
                                                     int* __restrict__ flags) {
    __shared__ int any;
    if (threadIdx.x == 0) any = 0;
    __syncthreads();
    const uint4* p = (const uint4*)raw;             // NG bytes = 16384 uint4
    int i = blockIdx.x * 256 + threadIdx.x;
    uint4 v = p[i];
    if ((v.x | v.y | v.z | v.w) & 0xFFFFFF00u) any = 1;
    __syncthreads();
    if (threadIdx.x == 0) flags[blockIdx.x] = any;
}

// ---------------------------------------------------------------------------
// k_prep: int mask (layout-adaptive) + touched map (gather-unmasked rows AND
// query-center rows) + bf16 col-major (B-layout) weights + bkv + zbias.
// touched[] must be zeroed before this kernel (hipMemsetAsync).
// ---------------------------------------------------------------------------
__global__ __launch_bounds__(256) void k_prep(const float* __restrict__ w_k,
                                              const float* __restrict__ w_v,
                                              const float* __restrict__ w_ff1,
                                              const float* __restrict__ w_ff2,
                                              const float* __restrict__ w_proj,
                                              const float* __restrict__ w_q,
                                              const float* __restrict__ b_k,
                                              const float* __restrict__ b_v,
                                              const float* __restrict__ pos_qx,
                                              const float* __restrict__ pos_qy,
                                              const float* __restrict__ pos_qz,
                                              const void* __restrict__ mask_raw,
                                              const int* __restrict__ gidx,
                                              const int* __restrict__ qidx,
                                              const int* __restrict__ flags,
                                              unsigned short* __restrict__ w_kv_t,
                                              unsigned short* __restrict__ w1_t,
                                              unsigned short* __restrict__ w2_t,
                                              unsigned short* __restrict__ wp_t,
                                              unsigned short* __restrict__ wq_t,
                                              unsigned short* __restrict__ wqp_t,
                                              float* __restrict__ bkv,
                                              float* __restrict__ zbias,
                                              int* __restrict__ mask_i,
                                              unsigned char* __restrict__ touched) {
    __shared__ int bl;
    if (threadIdx.x == 0) {
        int a = 0;
        #pragma unroll 8
        for (int i = 0; i < 64; i++) a |= flags[i];
        bl = a;
    }
    __syncthreads();
    int byteLayout = bl;
    int idx = blockIdx.x * 256 + threadIdx.x;       // grid 1024 -> 262144
    if (blockIdx.x == 0 && threadIdx.x < 512)
        bkv[threadIdx.x] = (threadIdx.x < 256) ? b_k[threadIdx.x]
                                               : b_v[threadIdx.x - 256];
    if (idx < QPL) zbias[idx] = 0.f;
    if (idx < NQ) touched[qidx[idx]] = 1;           // query-center rows need LN
    if (idx < NG) {
        int mv = byteLayout ? (int)((const unsigned char*)mask_raw)[idx]
                            : ((const int*)mask_raw)[idx];
        mask_i[idx] = (mv != 0) ? 1 : 0;
        if (mv == 0) touched[gidx[idx]] = 1;        // idempotent byte store
    }
    if (idx < 512 * 256) {
        int col = idx >> 8, j = idx & 255;
        float v = (col < 256) ? w_k[j * 256 + col] : w_v[j * 256 + (col - 256)];
        w_kv_t[idx] = f2bf(v);
    }
    if (idx < 512 * 256) {
        int n = idx >> 8, k = idx & 255;
        w1_t[idx] = f2bf(w_ff1[k * FFD + n]);
    }
    if (idx < 256 * 512) {
        int n = idx >> 9, k = idx & 511;
        w2_t[idx] = f2bf(w_ff2[k * CH + n]);
    }
    if (idx < 256 * 256) {
        int n = idx >> 8, k = idx & 255;
        wp_t[idx] = f2bf(w_proj[k * CH + n]);
        wq_t[idx] = f2bf(w_q[k * CH + n]);
    }
    if (idx < QPL * 256) {                          // wqp_t[col][k]
        int col = idx >> 8, k = idx & 255;
        float v = 0.f;
        if (col < QPN) {
            int h = col / QPW, r = col % QPW;
            int h2 = k >> 5, d = k & 31;
            if (h2 == h) {
                if (r < 15)      v = pos_qx[(h * DHD + d) * 15 + r];
                else if (r < 30) v = pos_qy[(h * DHD + d) * 15 + (r - 15)];
                else             v = pos_qz[(h * DHD + d) * 7  + (r - 30)];
            }
        }
        wqp_t[idx] = f2bf(v);
    }
}

// ---------------------------------------------------------------------------
// k_posc: comb[h][rx][ry][rz][d] = pos_kx[h][d][rx]+pos_ky[h][d][ry]+pos_kz[h][d][rz]
// ---------------------------------------------------------------------------
__global__ __launch_bounds__(256) void k_posc(const float* __restrict__ pos_kx,
                                              const float* __restrict__ pos_ky,
                                              const float* __restrict__ pos_kz,
                                              float* __restrict__ comb) {
    int idx = blockIdx.x * 256 + threadIdx.x;
    if (idx >= 8 * 15 * 15 * 7 * 32) return;
    int d = idx & 31, r = idx >> 5;
    int rz = r % 7;  r /= 7;
    int ry = r % 15; r /= 15;
    int rx = r % 15; int h = r / 15;
    comb[idx] = pos_kx[(h * DHD + d) * 15 + rx]
              + pos_ky[(h * DHD + d) * 15 + ry]
              + pos_kz[(h * DHD + d) * 7  + rz];
}

// ---------------------------------------------------------------------------
// k_ln: LayerNorm rows of x[nrows][256] -> bf16. One wave per row.
// If tch != nullptr, rows with tch[row]==0 are skipped (never consumed).
// ---------------------------------------------------------------------------
__global__ __launch_bounds__(256) void k_ln(const float* __restrict__ x,
                                            const float* __restrict__ g,
                                            const float* __restrict__ b,
                                            const unsigned char* __restrict__ tch,
                                            unsigned short* __restrict__ o,
                                            int nrows) {
    int wid = threadIdx.x >> 6, lane = threadIdx.x & 63;
    int row = blockIdx.x * 4 + wid;
    if (row >= nrows) return;
    if (tch && !tch[row]) return;                   // wave-uniform skip
    const float4 v = *(const float4*)(x + (size_t)row * CH + lane * 4);
    float s  = v.x + v.y + v.z + v.w;
    float sq = v.x * v.x + v.y * v.y + v.z * v.z + v.w * v.w;
    #pragma unroll
    for (int off = 1; off < 64; off <<= 1) {
        s  += __shfl_xor(s,  off);
        sq += __shfl_xor(sq, off);
    }
    float mu  = s * (1.f / CH);
    float var = sq * (1.f / CH) - mu * mu;
    float rs  = rsqrtf(var + 1e-5f);
    float4 gv = *(const float4*)(g + lane * 4);
    float4 bv = *(const float4*)(b + lane * 4);
    ushort4 ov;
    ov.x = f2bf((v.x - mu) * rs * gv.x + bv.x);
    ov.y = f2bf((v.y - mu) * rs * gv.y + bv.y);
    ov.z = f2bf((v.z - mu) * rs * gv.z + bv.z);
    ov.w = f2bf((v.w - mu) * rs * gv.w + bv.w);
    *(ushort4*)(o + (size_t)row * CH + lane * 4) = ov;
}

// ---------------------------------------------------------------------------
// k_qin: q_in[n][c] = bf16( ln_x[qidx[n]][c] + relu(coords[n]@w_pos + b_pos) )
// ---------------------------------------------------------------------------
__global__ __launch_bounds__(256) void k_qin(const unsigned short* __restrict__ ln_x,
                                             const float* __restrict__ coords,
                                             const int* __restrict__ qidx,
                                             const float* __restrict__ w_pos,
                                             const float* __restrict__ b_pos,
                                             unsigned short* __restrict__ qin) {
    int c = threadIdx.x;
    int nb = blockIdx.x * 8;
    float wp0 = w_pos[c], wp1 = w_pos[CH + c], wp2 = w_pos[2 * CH + c], bp = b_pos[c];
    #pragma unroll
    for (int qq = 0; qq < 8; qq++) {
        int n = nb + qq;
        float p = bp + coords[n * 3] * wp0 + coords[n * 3 + 1] * wp1 + coords[n * 3 + 2] * wp2;
        p = fmaxf(p, 0.f);
        int qi = qidx[n];
        qin[(size_t)n * CH + c] = f2bf(bf2f(ln_x[(size_t)qi * CH + c]) + p);
    }
}

// ---------------------------------------------------------------------------
// k_kv (R7 structure + touched pruning): dense kv projection.
// Tile 128 rows x 128 cols, 16 KB LDS (6+ blocks/CU — R9's 72 KB A-resident
// variant dropped occupancy to 15% and was slower). Untouched rows: fetch
// repointed to row 0 (harmless; their acc rows are discarded), stores skipped.
// Epilogue: LDS transpose -> coalesced 16B stores.
// ---------------------------------------------------------------------------
__global__ __launch_bounds__(256) void k_kv(const unsigned short* __restrict__ ln_x,
                                            const unsigned short* __restrict__ w_kv_t,
                                            const float* __restrict__ bkv,
                                            const unsigned char* __restrict__ touched,
                                            unsigned short* __restrict__ kv) {
    __shared__ __align__(16) unsigned short As[128 * 32];   // 8 KB
    __shared__ __align__(16) unsigned short Bs[128 * 32];   // 8 KB
    const int tid = threadIdx.x;
    const int w = tid >> 6, l = tid & 63;
    const int wr = w >> 1, wc = w & 1;
    const int rowbase = blockIdx.y * 128;
    const int col0 = blockIdx.x * 128;
    const int sr = l >> 2, sq = l & 3;
    int ra0 = rowbase + w * 16 + sr;
    int ra1 = rowbase + 64 + w * 16 + sr;
    int ok0 = (ra0 < MV) && touched[ra0 < MV ? ra0 : 0];
    int ok1 = (ra1 < MV) && touched[ra1 < MV ? ra1 : 0];
    const unsigned short* pa0 = ln_x + (size_t)(ok0 ? ra0 : 0) * CH + sq * 8;
    const unsigned short* pa1 = ln_x + (size_t)(ok1 ? ra1 : 0) * CH + sq * 8;
    const unsigned short* pb0 = w_kv_t + (size_t)(col0 + w * 16 + sr) * CH + sq * 8;
    const unsigned short* pb1 = w_kv_t + (size_t)(col0 + 64 + w * 16 + sr) * CH + sq * 8;
    unsigned short* lA0 = As + w * 512;
    unsigned short* lA1 = As + 2048 + w * 512;
    unsigned short* lB0 = Bs + w * 512;
    unsigned short* lB1 = Bs + 2048 + w * 512;

    f32x4 acc[4][4];
    #pragma unroll
    for (int mt = 0; mt < 4; mt++)
        #pragma unroll
        for (int nt = 0; nt < 4; nt++)
            acc[mt][nt] = (f32x4){0.f, 0.f, 0.f, 0.f};

    const int ml = l & 15, qd = l >> 4;
    for (int kk = 0; kk < CH; kk += 32) {
        __syncthreads();
        glds16(pa0 + kk, lA0);
        glds16(pa1 + kk, lA1);
        glds16(pb0 + kk, lB0);
        glds16(pb1 + kk, lB1);
        __syncthreads();
        bf16x8 af[4], bf[4];
        #pragma unroll
        for (int mt = 0; mt < 4; mt++)
            af[mt] = *(const bf16x8*)(As + (wr * 64 + mt * 16 + ml) * 32 + qd * 8);
        #pragma unroll
        for (int nt = 0; nt < 4; nt++)
            bf[nt] = *(const bf16x8*)(Bs + (wc * 64 + nt * 16 + ml) * 32 + qd * 8);
        #pragma unroll
        for (int mt = 0; mt < 4; mt++)
            #pragma unroll
            for (int nt = 0; nt < 4; nt++)
                acc[mt][nt] = __builtin_amdgcn_mfma_f32_16x16x32_bf16(af[mt], bf[nt], acc[mt][nt], 0, 0, 0);
    }

    // epilogue: bias + LDS transpose (reuse As: 2 bands x 16 x 128) + stores
    float bb[4];
    #pragma unroll
    for (int nt = 0; nt < 4; nt++)
        bb[nt] = bkv[col0 + wc * 64 + nt * 16 + ml];
    unsigned short* trs = As;
    #pragma unroll
    for (int mt = 0; mt < 4; mt++) {
        __syncthreads();
        #pragma unroll
        for (int nt = 0; nt < 4; nt++) {
            int lcol = wc * 64 + nt * 16 + ml;
            #pragma unroll
            for (int i = 0; i < 4; i++)
                trs[wr * 2048 + (qd * 4 + i) * 128 + lcol] = f2bf(acc[mt][nt][i] + bb[nt]);
        }
        __syncthreads();
        int rl = tid >> 4, cc = (tid & 15) * 8;
        int g0 = rowbase + mt * 16 + rl;
        int g1 = rowbase + 64 + mt * 16 + rl;
        if (g0 < MV && touched[g0])
            *(uint4*)(kv + (size_t)g0 * 512 + col0 + cc) = *(const uint4*)(trs + rl * 128 + cc);
        if (g1 < MV && touched[g1])
            *(uint4*)(kv + (size_t)g1 * 512 + col0 + cc) = *(const uint4*)(trs + 2048 + rl * 128 + cc);
    }
}

// ---------------------------------------------------------------------------
// k_mm<KD,EPI,LDO>: row GEMM, A[8192][KD] bf16 @ Bt[cols][KD] bf16.
//   EPI 0: relu -> bf16 at ld LDO            (FF1)
//   EPI 1: +bias+res -> fp32 at ld CH        (FF2)
//   EPI 2: +bias+res[qidx[row]] -> fp32      (proj)
//   EPI 3: +bias -> fp32 AND bf16 at ld CH   (q projection)
//   EPI 4: +bias -> fp32 at ld LDO           (qp tables)
// ---------------------------------------------------------------------------
template <int KD, int EPI, int LDO>
__global__ __launch_bounds__(256) void k_mm(const unsigned short* __restrict__ A,
                                            const unsigned short* __restrict__ Bt_g,
                                            const float* __restrict__ bias,
                                            const float* __restrict__ res,
                                            const int* __restrict__ qidx,
                                            unsigned short* __restrict__ out_bf,
                                            float* __restrict__ out_f) {
    __shared__ __align__(16) unsigned short As[128 * ASTR];
    __shared__ __align__(16) unsigned short Bs[64 * ASTR];
    int tid = threadIdx.x;
    int w = tid >> 6, l = tid & 63;
    int rowbase = blockIdx.y * 128;
    int col0 = blockIdx.x * 64;
    int r0 = tid >> 2, qt = tid & 3;
    const unsigned short* a0p = A + (size_t)(rowbase + r0) * KD + qt * 8;
    const unsigned short* a1p = A + (size_t)(rowbase + 64 + r0) * KD + qt * 8;

    f32x4 acc[2][4];
    #pragma unroll
    for (int mt = 0; mt < 2; mt++)
        #pragma unroll
        for (int nt = 0; nt < 4; nt++)
            acc[mt][nt] = (f32x4){0.f, 0.f, 0.f, 0.f};

    const int ml = l & 15, qd = l >> 4;
    for (int kk = 0; kk < KD; kk += 32) {
        __syncthreads();
        uint4 v0 = *(const uint4*)(a0p + kk);
        uint4 v1 = *(const uint4*)(a1p + kk);
        *(uint4*)(As + r0 * ASTR + qt * 8)        = v0;
        *(uint4*)(As + (64 + r0) * ASTR + qt * 8) = v1;
        {
            uint4 bv = *(const uint4*)(Bt_g + (size_t)(col0 + r0) * KD + kk + qt * 8);
            *(uint4*)(Bs + r0 * ASTR + qt * 8) = bv;
        }
        __syncthreads();
        bf16x8 a0 = *(const bf16x8*)(As + (w * 32 + ml) * ASTR + qd * 8);
        bf16x8 a1 = *(const bf16x8*)(As + (w * 32 + 16 + ml) * ASTR + qd * 8);
        #pragma unroll
        for (int nt = 0; nt < 4; nt++) {
            bf16x8 bb = *(const bf16x8*)(Bs + (nt * 16 + ml) * ASTR + qd * 8);
            acc[0][nt] = __builtin_amdgcn_mfma_f32_16x16x32_bf16(a0, bb, acc[0][nt], 0, 0, 0);
            acc[1][nt] = __builtin_amdgcn_mfma_f32_16x16x32_bf16(a1, bb, acc[1][nt], 0, 0, 0);
        }
    }

    #pragma unroll
    for (int nt = 0; nt < 4; nt++) {
        int col = col0 + nt * 16 + ml;
        float bv = bias[col];
        #pragma unroll
        for (int mt = 0; mt < 2; mt++) {
            int rl = w * 32 + mt * 16 + qd * 4;
            #pragma unroll
            for (int i = 0; i < 4; i++) {
                int row = rowbase + rl + i;
                float v = acc[mt][nt][i] + bv;
                if (EPI == 0) {
                    out_bf[(size_t)row * LDO + col] = f2bf(fmaxf(v, 0.f));
                } else if (EPI == 1) {
                    out_f[(size_t)row * CH + col] = v + res[(size_t)row * CH + col];
                } else if (EPI == 2) {
                    int qi = qidx[row];
                    out_f[(size_t)row * CH + col] = v + res[(size_t)qi * CH + col];
                } else if (EPI == 3) {
                    out_f[(size_t)row * CH + col] = v;
                    out_bf[(size_t)row * CH + col] = f2bf(v);
                } else {
                    out_f[(size_t)row * LDO + col] = v;
                }
            }
        }
    }
}

// ---------------------------------------------------------------------------
// k_attn3: staged-LDS fused attention (unchanged from R9 — left the top-5).
// ---------------------------------------------------------------------------
__global__ __launch_bounds__(256) void k_attn3(const float* __restrict__ qbuf,
                                               const float* __restrict__ qp,
                                               const unsigned short* __restrict__ kvmat,
                                               const int* __restrict__ gidx,
                                               const int* __restrict__ mask_i,
                                               const int* __restrict__ rel_x,
                                               const int* __restrict__ rel_y,
                                               const int* __restrict__ rel_z,
                                               const float* __restrict__ comb,
                                               const float* __restrict__ b_v,
                                               unsigned short* __restrict__ attnln) {
    __shared__ float q_s[2 * 256];
    __shared__ float qp_s[2 * QPL];                 // reused as partial sums in part 2
    __shared__ float attn_s[2 * 256];
    __shared__ int   mask_s[64];
    __shared__ int   gidx_s[64];
    __shared__ __align__(16) unsigned short ks[64 * KSTR];   // 33 KB

    int tid = threadIdx.x;
    int qb = blockIdx.x * 2;
    for (int i = tid; i < 512; i += 256) q_s[i] = qbuf[(size_t)qb * CH + i];
    for (int i = tid; i < 2 * QPL; i += 256) qp_s[i] = qp[(size_t)qb * QPL + i];
    if (tid < 64) {
        mask_s[tid] = mask_i[qb * 32 + tid];
        gidx_s[tid] = gidx[qb * 32 + tid];
    }
    __syncthreads();

    // ---- Phase A: stage k-parts (rows' first 512 B), coalesced ----
    const int srow = tid >> 5;                      // 0..7
    const int schk = tid & 31;                      // 16 B chunk within row
    uint4 kreg[8];
    #pragma unroll
    for (int j = 0; j < 8; j++) {
        int r = j * 8 + srow;
        uint4 v = {0u, 0u, 0u, 0u};
        if (!mask_s[r])
            v = *(const uint4*)(kvmat + (size_t)gidx_s[r] * 512 + schk * 8);
        kreg[j] = v;
    }
    #pragma unroll
    for (int j = 0; j < 8; j++)
        *(uint4*)(ks + (j * 8 + srow) * KSTR + schk * 8) = kreg[j];
    __syncthreads();

    // ---- Part 1: logits + softmax from LDS ----
    int h = tid >> 5, k = tid & 31;
    const float scale = 0.17677669529663687f;       // 32^-0.5
    for (int qq = 0; qq < 2; qq++) {
        int n = qb + qq;
        int gi = n * KN + k;
        int r = qq * 32 + k;
        int mk = mask_s[r];
        float lg = -1e9f;
        if (!mk) {
            int rx = rel_x[gi], ry = rel_y[gi], rz = rel_z[gi];
            const unsigned short* kp = ks + r * KSTR + h * 32;
            float kv[32];
            #pragma unroll
            for (int j = 0; j < 4; j++) {
                uint4 u = *(const uint4*)(kp + j * 8);
                kv[j * 8 + 0] = bf2f((unsigned short)(u.x & 0xFFFF));
                kv[j * 8 + 1] = bf2f((unsigned short)(u.x >> 16));
                kv[j * 8 + 2] = bf2f((unsigned short)(u.y & 0xFFFF));
                kv[j * 8 + 3] = bf2f((unsigned short)(u.y >> 16));
                kv[j * 8 + 4] = bf2f((unsigned short)(u.z & 0xFFFF));
                kv[j * 8 + 5] = bf2f((unsigned short)(u.z >> 16));
                kv[j * 8 + 6] = bf2f((unsigned short)(u.w & 0xFFFF));
                kv[j * 8 + 7] = bf2f((unsigned short)(u.w >> 16));
            }
            const float* cp = comb + ((((h * 15 + rx) * 15 + ry) * 7 + rz) << 5);
            float s1 = 0.f, s2 = 0.f;
            const float* qrow = q_s + qq * CH + h * DHD;
            #pragma unroll
            for (int d = 0; d < 32; d++) {
                s1 += kv[d] * qrow[d];
                s2 += kv[d] * cp[d];
            }
            lg = s1 * scale + s2
               + qp_s[qq * QPL + h * QPW + rx]
               + qp_s[qq * QPL + h * QPW + 15 + ry]
               + qp_s[qq * QPL + h * QPW + 30 + rz];
        }
        float mx = lg;
        #pragma unroll
        for (int off = 1; off <= 16; off <<= 1) mx = fmaxf(mx, __shfl_xor(mx, off));
        float e = mk ? 0.f : __expf(lg - mx);
        float sm = e;
        #pragma unroll
        for (int off = 1; off <= 16; off <<= 1) sm += __shfl_xor(sm, off);
        attn_s[qq * 256 + tid] = (sm > 0.f) ? e / sm : 0.f;
    }

    // ---- Phase B: restage v-parts into the same buffer ----
    #pragma unroll
    for (int j = 0; j < 8; j++) {
        int r = j * 8 + srow;
        uint4 v = {0u, 0u, 0u, 0u};
        if (!mask_s[r])
            v = *(const uint4*)(kvmat + (size_t)gidx_s[r] * 512 + 256 + schk * 8);
        kreg[j] = v;
    }
    __syncthreads();                                // part-1 ks reads + attn_s writes done
    #pragma unroll
    for (int j = 0; j < 8; j++)
        *(uint4*)(ks + (j * 8 + srow) * KSTR + schk * 8) = kreg[j];
    __syncthreads();

    // ---- Part 2: weighted v from LDS. wave w = (query w>>1, half w&1) ----
    int w = tid >> 6, l = tid & 63;
    int q2 = w >> 1, kh = w & 1;
    int hh = l >> 3;                                // head of col group l*4
    float a0 = 0.f, a1 = 0.f, a2 = 0.f, a3 = 0.f;
    #pragma unroll
    for (int i = 0; i < 16; i++) {
        int kk = kh * 16 + i;
        int r = q2 * 32 + kk;
        float av = attn_s[q2 * 256 + hh * 32 + kk]; // 0 for masked
        ushort4 v4 = *(const ushort4*)(ks + r * KSTR + l * 4);
        a0 += av * bf2f(v4.x);
        a1 += av * bf2f(v4.y);
        a2 += av * bf2f(v4.z);
        a3 += av * bf2f(v4.w);
    }
    if (kh == 1) {
        float4 pv = {a0, a1, a2, a3};
        *(float4*)(qp_s + q2 * 256 + l * 4) = pv;   // qp_s repurposed (>=512 floats)
    }
    __syncthreads();
    if (kh == 0) {
        float4 pv = *(const float4*)(qp_s + q2 * 256 + l * 4);
        a0 += pv.x; a1 += pv.y; a2 += pv.z; a3 += pv.w;
        int nm = 0;
        #pragma unroll
        for (int kk = 0; kk < 32; kk++) nm += 1 - mask_s[q2 * 32 + kk];
        int col = l * 4;
        if (nm == 0) {
            a0 = b_v[col]; a1 = b_v[col + 1]; a2 = b_v[col + 2]; a3 = b_v[col + 3];
        }
        ushort4 o;
        o.x = f2bf(a0); o.y = f2bf(a1); o.z = f2bf(a2); o.w = f2bf(a3);
        *(ushort4*)(attnln + (size_t)(qb + q2) * CH + col) = o;
    }
}

// ---------------------------------------------------------------------------
extern "C" void kernel_launch(void* const* d_in, const int* in_sizes, int n_in,
                              void* d_out, int out_size, void* d_ws, size_t ws_size,
                              hipStream_t stream) {
    (void)in_sizes; (void)n_in; (void)out_size; (void)ws_size;
    const float* vox    = (const float*)d_in[0];
    const float* coords = (const float*)d_in[1];
    const int*   qidx   = (const int*)d_in[2];
    const int*   gidx   = (const int*)d_in[3];
    const void*  mraw   = d_in[4];
    const int*   rel_x  = (const int*)d_in[5];
    const int*   rel_y  = (const int*)d_in[6];
    const int*   rel_z  = (const int*)d_in[7];
    const float* w_pos  = (const float*)d_in[8];
    const float* b_pos  = (const float*)d_in[9];
    const float* w_q    = (const float*)d_in[10];
    const float* b_q    = (const float*)d_in[11];
    const float* w_k    = (const float*)d_in[12];
    const float* b_k    = (const float*)d_in[13];
    const float* w_v    = (const float*)d_in[14];
    const float* b_v    = (const float*)d_in[15];
    const float* w_proj = (const float*)d_in[16];
    const float* b_proj = (const float*)d_in[17];
    const float* ln1_g  = (const float*)d_in[18];
    const float* ln1_b  = (const float*)d_in[19];
    const float* ln2_g  = (const float*)d_in[20];
    const float* ln2_b  = (const float*)d_in[21];
    const float* w_ff1  = (const float*)d_in[22];
    const float* b_ff1  = (const float*)d_in[23];
    const float* w_ff2  = (const float*)d_in[24];
    const float* b_ff2  = (const float*)d_in[25];
    const float* pos_qx = (const float*)d_in[26];
    const float* pos_qy = (const float*)d_in[27];
    const float* pos_qz = (const float*)d_in[28];
    const float* pos_kx = (const float*)d_in[29];
    const float* pos_ky = (const float*)d_in[30];
    const float* pos_kz = (const float*)d_in[31];

    // workspace carve (~205 MB total)
    char* p = (char*)d_ws;
    auto take = [&](size_t n) { char* r = p; p += (n + 255) & ~(size_t)255; return r; };
    unsigned short* ln_x    = (unsigned short*)take((size_t)MV * CH * 2);   // 51.2 MB
    unsigned short* w_kv_t  = (unsigned short*)take((size_t)512 * 256 * 2);
    unsigned short* w1_t    = (unsigned short*)take((size_t)512 * 256 * 2);
    unsigned short* w2_t    = (unsigned short*)take((size_t)256 * 512 * 2);
    unsigned short* wp_t    = (unsigned short*)take((size_t)256 * 256 * 2);
    unsigned short* wq_t    = (unsigned short*)take((size_t)256 * 256 * 2);
    unsigned short* wqp_t   = (unsigned short*)take((size_t)QPL * 256 * 2);
    float*          bkv     = (float*)take(512 * 4);
    float*          zbias   = (float*)take(QPL * 4);
    int*            flags   = (int*)take(64 * 4);
    int*            mask_i  = (int*)take((size_t)NG * 4);                   // 1.05 MB
    unsigned char*  touched = (unsigned char*)take(MV);                     // 0.1 MB
    float*          comb    = (float*)take((size_t)8 * 15 * 15 * 7 * 32 * 4); // 1.6 MB
    unsigned short* qin     = (unsigned short*)take((size_t)NQ * CH * 2);   // 4.2 MB
    float*          qbuf    = (float*)take((size_t)NQ * CH * 4);            // 8.4 MB
    unsigned short* qbf     = (unsigned short*)take((size_t)NQ * CH * 2);   // 4.2 MB
    float*          qp      = (float*)take((size_t)NQ * QPL * 4);           // 10.5 MB
    unsigned short* kvmat   = (unsigned short*)take((size_t)MV * 512 * 2);  // 102.4 MB
    unsigned short* attnln  = (unsigned short*)take((size_t)NQ * CH * 2);   // 4.2 MB
    float*          actbuf  = (float*)take((size_t)NQ * CH * 4);            // 8.4 MB
    unsigned short* actln   = (unsigned short*)take((size_t)NQ * CH * 2);   // 4.2 MB
    unsigned short* hbuf    = (unsigned short*)take((size_t)NQ * FFD * 2);  // 8.4 MB

    hipMemsetAsync(touched, 0, MV, stream);
    hipLaunchKernelGGL(k_detect_mask, dim3(64), dim3(256), 0, stream,
                       (const unsigned char*)mraw, flags);
    hipLaunchKernelGGL(k_prep, dim3(NG / 256), dim3(256), 0, stream,
                       w_k, w_v, w_ff1, w_ff2, w_proj, w_q, b_k, b_v,
                       pos_qx, pos_qy, pos_qz, mraw, gidx, qidx, flags,
                       w_kv_t, w1_t, w2_t, wp_t, wq_t, wqp_t, bkv, zbias,
                       mask_i, touched);
    hipLaunchKernelGGL(k_posc, dim3((8 * 15 * 15 * 7 * 32 + 255) / 256), dim3(256), 0, stream,
                       pos_kx, pos_ky, pos_kz, comb);
    hipLaunchKernelGGL(k_ln, dim3(MV / 4 + 1), dim3(256), 0, stream,
                       vox, ln1_g, ln1_b, touched, ln_x, MV);
    hipLaunchKernelGGL(k_qin, dim3(NQ / 8), dim3(256), 0, stream,
                       ln_x, coords, qidx, w_pos, b_pos, qin);
    // dense kv projection: kv[m][512] = ln_x @ [w_k|w_v] + [b_k|b_v]
    hipLaunchKernelGGL(k_kv, dim3(4, (MV + 127) / 128), dim3(256), 0, stream,
                       ln_x, w_kv_t, bkv, touched, kvmat);
    // q = qin @ wq_t + b_q  (fp32 + bf16)
    hipLaunchKernelGGL(HIP_KERNEL_NAME(k_mm<256, 3, CH>), dim3(4, NQ / 128), dim3(256), 0, stream,
                       qin, wq_t, b_q, (const float*)nullptr, (const int*)nullptr,
                       qbf, qbuf);
    // qp = qbf @ wqp_t  (fp32, ld QPL)
    hipLaunchKernelGGL(HIP_KERNEL_NAME(k_mm<256, 4, QPL>), dim3(QPL / 64, NQ / 128), dim3(256), 0, stream,
                       qbf, wqp_t, zbias, (const float*)nullptr, (const int*)nullptr,
                       (unsigned short*)nullptr, qp);
    // staged-LDS fused attention
    hipLaunchKernelGGL(k_attn3, dim3(NQ / 2), dim3(256), 0, stream,
                       qbuf, qp, kvmat, gidx, mask_i, rel_x, rel_y, rel_z,
                       comb, b_v, attnln);
    // proj: act = attn_bf16 @ wp_t + b_proj + vox[qidx]
    hipLaunchKernelGGL(HIP_KERNEL_NAME(k_mm<256, 2, CH>), dim3(4, NQ / 128), dim3(256), 0, stream,
                       attnln, wp_t, b_proj, vox, qidx,
                       (unsigned short*)nullptr, actbuf);
    hipLaunchKernelGGL(k_ln, dim3(NQ / 4), dim3(256), 0, stream,
                       actbuf, ln2_g, ln2_b, (const unsigned char*)nullptr, actln, NQ);
    // FF1: h = relu(actln @ w1_t + b_ff1)
    hipLaunchKernelGGL(HIP_KERNEL_NAME(k_mm<256, 0, FFD>), dim3(8, NQ / 128), dim3(256), 0, stream,
                       actln, w1_t, b_ff1, (const float*)nullptr, (const int*)nullptr,
                       hbuf, (float*)nullptr);
    // FF2: out = h @ w2_t + b_ff2 + act
    hipLaunchKernelGGL(HIP_KERNEL_NAME(k_mm<512, 1, CH>), dim3(4, NQ / 128), dim3(256), 0, stream,
                       hbuf, w2_t, b_ff2, actbuf, (const int*)nullptr,
                       (unsigned short*)nullptr, (float*)d_out);
}

// Round 11
// 386.451 us; speedup vs baseline: 1.0785x; 1.0119x over previous
//
#include <hip/hip_runtime.h>
#include <hip/hip_bf16.h>
#include <math.h>

// Problem constants (fixed by the reference)
#define MV   100000          // voxels
#define NQ   8192            // queries
#define KN   32              // neighbors per query
#define CH   256             // channels
#define NH   8               // heads
#define DHD  32              // head dim
#define FFD  512             // FF hidden
#define NG   (NQ*KN)         // 262144 gathered rows
#define QPW  37              // 15+15+7 rel-pos columns per head (q-side)
#define QPN  (NH*QPW)        // 296
#define QCL  576             // q(256) + qp(320) concatenated row stride
#define ASTR 40              // padded LDS stride for k_mm
#define KSTR 264             // attn LDS row stride in shorts (528 B -> 4-way banks)

typedef __bf16 bf16x8 __attribute__((ext_vector_type(8)));
typedef float  f32x4  __attribute__((ext_vector_type(4)));

__device__ __forceinline__ float bf2f(unsigned short u) {
    return __uint_as_float(((unsigned int)u) << 16);
}
__device__ __forceinline__ unsigned short f2bf(float f) {
    unsigned int x = __float_as_uint(f);
    unsigned int r = x + 0x7FFFu + ((x >> 16) & 1u);   // RNE
    return (unsigned short)(r >> 16);
}
// async global->LDS, 16 B per lane; LDS dest = wave-uniform base + lane*16
__device__ __forceinline__ void glds16(const unsigned short* g, unsigned short* l) {
    __builtin_amdgcn_global_load_lds(
        (const __attribute__((address_space(1))) void*)g,
        (__attribute__((address_space(3))) void*)l, 16, 0, 0);
}

// ---------------------------------------------------------------------------
// k_detect_mask: gather_mask may ship as int32 (0/1) or raw 1-byte bools.
// ---------------------------------------------------------------------------
__global__ __launch_bounds__(256) void k_detect_mask(const unsigned char* __restrict__ raw,
                                                     int* __restrict__ flags) {
    __shared__ int any;
    if (threadIdx.x == 0) any = 0;
    __syncthreads();
    const uint4* p = (const uint4*)raw;             // NG bytes = 16384 uint4
    int i = blockIdx.x * 256 + threadIdx.x;
    uint4 v = p[i];
    if ((v.x | v.y | v.z | v.w) & 0xFFFFFF00u) any = 1;
    __syncthreads();
    if (threadIdx.x == 0) flags[blockIdx.x] = any;
}

// ---------------------------------------------------------------------------
// k_prep: int mask (layout-adaptive) + touched map (gather-unmasked rows AND
// query-center rows) + bf16 col-major (B-layout) weights + bkv + biases.
// wqcat cols 0..255 = w_q columns; cols 256..575 filled by k_wqp.
// touched[] must be zeroed before this kernel (hipMemsetAsync).
// ---------------------------------------------------------------------------
__global__ __launch_bounds__(256) void k_prep(const float* __restrict__ w_k,
                                              const float* __restrict__ w_v,
                                              const float* __restrict__ w_ff1,
                                              const float* __restrict__ w_ff2,
                                              const float* __restrict__ w_proj,
                                              const float* __restrict__ w_q,
                                              const float* __restrict__ b_k,
                                              const float* __restrict__ b_v,
                                              const float* __restrict__ b_q,
                                              const void* __restrict__ mask_raw,
                                              const int* __restrict__ gidx,
                                              const int* __restrict__ qidx,
                                              const int* __restrict__ flags,
                                              unsigned short* __restrict__ w_kv_t,
                                              unsigned short* __restrict__ w1_t,
                                              unsigned short* __restrict__ w2_t,
                                              unsigned short* __restrict__ wp_t,
                                              unsigned short* __restrict__ wqcat,
                                              float* __restrict__ bkv,
                                              float* __restrict__ bqcat,
                                              int* __restrict__ mask_i,
                                              unsigned char* __restrict__ touched) {
    __shared__ int bl;
    if (threadIdx.x == 0) {
        int a = 0;
        #pragma unroll 8
        for (int i = 0; i < 64; i++) a |= flags[i];
        bl = a;
    }
    __syncthreads();
    int byteLayout = bl;
    int idx = blockIdx.x * 256 + threadIdx.x;       // grid 1024 -> 262144
    if (blockIdx.x == 0 && threadIdx.x < 512)
        bkv[threadIdx.x] = (threadIdx.x < 256) ? b_k[threadIdx.x]
                                               : b_v[threadIdx.x - 256];
    if (blockIdx.x == 1) bqcat[threadIdx.x] = (threadIdx.x < 256) ? b_q[threadIdx.x] : 0.f;
    if (blockIdx.x == 2 && threadIdx.x < QCL - 256) bqcat[256 + threadIdx.x] = 0.f;
    if (idx < NQ) touched[qidx[idx]] = 1;           // query-center rows need LN
    if (idx < NG) {
        int mv = byteLayout ? (int)((const unsigned char*)mask_raw)[idx]
                            : ((const int*)mask_raw)[idx];
        mask_i[idx] = (mv != 0) ? 1 : 0;
        if (mv == 0) touched[gidx[idx]] = 1;        // idempotent byte store
    }
    if (idx < 512 * 256) {
        int col = idx >> 8, j = idx & 255;
        float v = (col < 256) ? w_k[j * 256 + col] : w_v[j * 256 + (col - 256)];
        w_kv_t[idx] = f2bf(v);
    }
    if (idx < 512 * 256) {
        int n = idx >> 8, k = idx & 255;
        w1_t[idx] = f2bf(w_ff1[k * FFD + n]);
    }
    if (idx < 256 * 512) {
        int n = idx >> 9, k = idx & 511;
        w2_t[idx] = f2bf(w_ff2[k * CH + n]);
    }
    if (idx < 256 * 256) {
        int n = idx >> 8, k = idx & 255;
        wp_t[idx] = f2bf(w_proj[k * CH + n]);
        wqcat[idx] = f2bf(w_q[k * CH + n]);
    }
}

// ---------------------------------------------------------------------------
// k_wqp: combined q-side rel-pos weight (folds qp = q@T into qin@(Wq@T)):
//   wqcat[256+col][k] = bf16( sum_d w_q[k][h*32+d] * T[h][d][r] )
//   bqcat[256+col]    =       sum_d b_q[h*32+d]    * T[h][d][r]
// col=(h,r) over 296 real cols (rest zero). 320 blocks.
// ---------------------------------------------------------------------------
__global__ __launch_bounds__(256) void k_wqp(const float* __restrict__ w_q,
                                             const float* __restrict__ b_q,
                                             const float* __restrict__ pos_qx,
                                             const float* __restrict__ pos_qy,
                                             const float* __restrict__ pos_qz,
                                             unsigned short* __restrict__ wqcat,
                                             float* __restrict__ bqcat) {
    int col = blockIdx.x;                 // 0..319
    int k = threadIdx.x;                  // 0..255
    float acc = 0.f, bacc = 0.f;
    if (col < QPN) {
        int h = col / QPW, r = col % QPW;
        const float* T; int rr, R;
        if (r < 15)      { T = pos_qx; rr = r;      R = 15; }
        else if (r < 30) { T = pos_qy; rr = r - 15; R = 15; }
        else             { T = pos_qz; rr = r - 30; R = 7;  }
        #pragma unroll
        for (int d = 0; d < DHD; d++) {
            float t = T[(h * DHD + d) * R + rr];
            acc += w_q[k * CH + h * DHD + d] * t;
            if (k == 0) bacc += b_q[h * DHD + d] * t;
        }
    }
    wqcat[(size_t)(256 + col) * CH + k] = f2bf(acc);
    if (k == 0) bqcat[256 + col] = bacc;
}

// ---------------------------------------------------------------------------
// k_posc: comb[h][rx][ry][rz][d] = pos_kx[h][d][rx]+pos_ky[h][d][ry]+pos_kz[h][d][rz]
// ---------------------------------------------------------------------------
__global__ __launch_bounds__(256) void k_posc(const float* __restrict__ pos_kx,
                                              const float* __restrict__ pos_ky,
                                              const float* __restrict__ pos_kz,
                                              float* __restrict__ comb) {
    int idx = blockIdx.x * 256 + threadIdx.x;
    if (idx >= 8 * 15 * 15 * 7 * 32) return;
    int d = idx & 31, r = idx >> 5;
    int rz = r % 7;  r /= 7;
    int ry = r % 15; r /= 15;
    int rx = r % 15; int h = r / 15;
    comb[idx] = pos_kx[(h * DHD + d) * 15 + rx]
              + pos_ky[(h * DHD + d) * 15 + ry]
              + pos_kz[(h * DHD + d) * 7  + rz];
}

// ---------------------------------------------------------------------------
// k_ln: LayerNorm rows of x[nrows][256] -> bf16. One wave per row.
// If tch != nullptr, rows with tch[row]==0 are skipped (never consumed).
// ---------------------------------------------------------------------------
__global__ __launch_bounds__(256) void k_ln(const float* __restrict__ x,
                                            const float* __restrict__ g,
                                            const float* __restrict__ b,
                                            const unsigned char* __restrict__ tch,
                                            unsigned short* __restrict__ o,
                                            int nrows) {
    int wid = threadIdx.x >> 6, lane = threadIdx.x & 63;
    int row = blockIdx.x * 4 + wid;
    if (row >= nrows) return;
    if (tch && !tch[row]) return;                   // wave-uniform skip
    const float4 v = *(const float4*)(x + (size_t)row * CH + lane * 4);
    float s  = v.x + v.y + v.z + v.w;
    float sq = v.x * v.x + v.y * v.y + v.z * v.z + v.w * v.w;
    #pragma unroll
    for (int off = 1; off < 64; off <<= 1) {
        s  += __shfl_xor(s,  off);
        sq += __shfl_xor(sq, off);
    }
    float mu  = s * (1.f / CH);
    float var = sq * (1.f / CH) - mu * mu;
    float rs  = rsqrtf(var + 1e-5f);
    float4 gv = *(const float4*)(g + lane * 4);
    float4 bv = *(const float4*)(b + lane * 4);
    ushort4 ov;
    ov.x = f2bf((v.x - mu) * rs * gv.x + bv.x);
    ov.y = f2bf((v.y - mu) * rs * gv.y + bv.y);
    ov.z = f2bf((v.z - mu) * rs * gv.z + bv.z);
    ov.w = f2bf((v.w - mu) * rs * gv.w + bv.w);
    *(ushort4*)(o + (size_t)row * CH + lane * 4) = ov;
}

// ---------------------------------------------------------------------------
// k_qin: q_in[n][c] = bf16( ln_x[qidx[n]][c] + relu(coords[n]@w_pos + b_pos) )
// ---------------------------------------------------------------------------
__global__ __launch_bounds__(256) void k_qin(const unsigned short* __restrict__ ln_x,
                                             const float* __restrict__ coords,
                                             const int* __restrict__ qidx,
                                             const float* __restrict__ w_pos,
                                             const float* __restrict__ b_pos,
                                             unsigned short* __restrict__ qin) {
    int c = threadIdx.x;
    int nb = blockIdx.x * 8;
    float wp0 = w_pos[c], wp1 = w_pos[CH + c], wp2 = w_pos[2 * CH + c], bp = b_pos[c];
    #pragma unroll
    for (int qq = 0; qq < 8; qq++) {
        int n = nb + qq;
        float p = bp + coords[n * 3] * wp0 + coords[n * 3 + 1] * wp1 + coords[n * 3 + 2] * wp2;
        p = fmaxf(p, 0.f);
        int qi = qidx[n];
        qin[(size_t)n * CH + c] = f2bf(bf2f(ln_x[(size_t)qi * CH + c]) + p);
    }
}

// ---------------------------------------------------------------------------
// k_kv v3: dense kv projection. Tile 128x128, BK=64 (2 k-chunks per staging
// round: 4 rounds x 2 barriers = 8 barriers, 32 MFMA per barrier-pair) +
// SINGLE-PASS epilogue: full 128x128 bf16 tile transposed through the 32 KB
// LDS in one barrier-pair, stores 4 KB/wave-round coalesced. (R10's version
// paid 24 barriers/block -> MfmaUtil 17%, stuck at ~61us across traffic
// levels.) Untouched rows: fetch repointed to row 0, stores skipped.
// ---------------------------------------------------------------------------
__global__ __launch_bounds__(256) void k_kv(const unsigned short* __restrict__ ln_x,
                                            const unsigned short* __restrict__ w_kv_t,
                                            const float* __restrict__ bkv,
                                            const unsigned char* __restrict__ touched,
                                            unsigned short* __restrict__ kv) {
    __shared__ __align__(16) unsigned short S[16384];       // 32 KB
    unsigned short* As = S;                                  // 2 x [128][32]
    unsigned short* Bs = S + 8192;                           // 2 x [128][32]
    const int tid = threadIdx.x;
    const int w = tid >> 6, l = tid & 63;
    const int wr = w >> 1, wc = w & 1;
    const int rowbase = blockIdx.y * 128;
    const int col0 = blockIdx.x * 128;
    const int sr = l >> 2, sq = l & 3;
    int ra0 = rowbase + w * 16 + sr;
    int ra1 = rowbase + 64 + w * 16 + sr;
    int ok0 = (ra0 < MV) && touched[ra0 < MV ? ra0 : 0];
    int ok1 = (ra1 < MV) && touched[ra1 < MV ? ra1 : 0];
    const unsigned short* pa0 = ln_x + (size_t)(ok0 ? ra0 : 0) * CH + sq * 8;
    const unsigned short* pa1 = ln_x + (size_t)(ok1 ? ra1 : 0) * CH + sq * 8;
    const unsigned short* pb0 = w_kv_t + (size_t)(col0 + w * 16 + sr) * CH + sq * 8;
    const unsigned short* pb1 = w_kv_t + (size_t)(col0 + 64 + w * 16 + sr) * CH + sq * 8;
    unsigned short* lA0 = As + w * 512;
    unsigned short* lA1 = As + 2048 + w * 512;
    unsigned short* lB0 = Bs + w * 512;
    unsigned short* lB1 = Bs + 2048 + w * 512;

    f32x4 acc[4][4];
    #pragma unroll
    for (int mt = 0; mt < 4; mt++)
        #pragma unroll
        for (int nt = 0; nt < 4; nt++)
            acc[mt][nt] = (f32x4){0.f, 0.f, 0.f, 0.f};

    const int ml = l & 15, qd = l >> 4;
    for (int kk = 0; kk < CH; kk += 64) {
        __syncthreads();
        glds16(pa0 + kk, lA0);
        glds16(pa1 + kk, lA1);
        glds16(pb0 + kk, lB0);
        glds16(pb1 + kk, lB1);
        glds16(pa0 + kk + 32, lA0 + 4096);
        glds16(pa1 + kk + 32, lA1 + 4096);
        glds16(pb0 + kk + 32, lB0 + 4096);
        glds16(pb1 + kk + 32, lB1 + 4096);
        __syncthreads();
        #pragma unroll
        for (int c2 = 0; c2 < 2; c2++) {
            const unsigned short* Ac = As + c2 * 4096;
            const unsigned short* Bc = Bs + c2 * 4096;
            bf16x8 af[4], bf[4];
            #pragma unroll
            for (int mt = 0; mt < 4; mt++)
                af[mt] = *(const bf16x8*)(Ac + (wr * 64 + mt * 16 + ml) * 32 + qd * 8);
            #pragma unroll
            for (int nt = 0; nt < 4; nt++)
                bf[nt] = *(const bf16x8*)(Bc + (wc * 64 + nt * 16 + ml) * 32 + qd * 8);
            #pragma unroll
            for (int mt = 0; mt < 4; mt++)
                #pragma unroll
                for (int nt = 0; nt < 4; nt++)
                    acc[mt][nt] = __builtin_amdgcn_mfma_f32_16x16x32_bf16(af[mt], bf[nt], acc[mt][nt], 0, 0, 0);
        }
    }

    // single-pass epilogue: bias + full-tile transpose in S + coalesced stores
    float bb[4];
    #pragma unroll
    for (int nt = 0; nt < 4; nt++)
        bb[nt] = bkv[col0 + wc * 64 + nt * 16 + ml];
    __syncthreads();                                // last MFMA reads of S done
    #pragma unroll
    for (int mt = 0; mt < 4; mt++)
        #pragma unroll
        for (int nt = 0; nt < 4; nt++) {
            int col = wc * 64 + nt * 16 + ml;
            #pragma unroll
            for (int i = 0; i < 4; i++) {
                int row = wr * 64 + mt * 16 + qd * 4 + i;
                S[row * 128 + col] = f2bf(acc[mt][nt][i] + bb[nt]);
            }
        }
    __syncthreads();
    #pragma unroll
    for (int j = 0; j < 8; j++) {
        int chunk = j * 256 + tid;                  // rows j*16..j*16+15, coalesced
        int row = chunk >> 4, cc = (chunk & 15) * 8;
        int g = rowbase + row;
        if (g < MV && touched[g])
            *(uint4*)(kv + (size_t)g * 512 + col0 + cc) = *(const uint4*)(S + row * 128 + cc);
    }
}

// ---------------------------------------------------------------------------
// k_mm<KD,EPI,LDO>: row GEMM, A[8192][KD] bf16 @ Bt[cols][KD] bf16.
//   EPI 0: relu -> bf16 at ld LDO            (FF1)
//   EPI 1: +bias+res -> fp32 at ld CH        (FF2)
//   EPI 2: +bias+res[qidx[row]] -> fp32      (proj)
//   EPI 4: +bias -> fp32 at ld LDO           (q‖qp concatenated)
// ---------------------------------------------------------------------------
template <int KD, int EPI, int LDO>
__global__ __launch_bounds__(256) void k_mm(const unsigned short* __restrict__ A,
                                            const unsigned short* __restrict__ Bt_g,
                                            const float* __restrict__ bias,
                                            const float* __restrict__ res,
                                            const int* __restrict__ qidx,
                                            unsigned short* __restrict__ out_bf,
                                            float* __restrict__ out_f) {
    __shared__ __align__(16) unsigned short As[128 * ASTR];
    __shared__ __align__(16) unsigned short Bs[64 * ASTR];
    int tid = threadIdx.x;
    int w = tid >> 6, l = tid & 63;
    int rowbase = blockIdx.y * 128;
    int col0 = blockIdx.x * 64;
    int r0 = tid >> 2, qt = tid & 3;
    const unsigned short* a0p = A + (size_t)(rowbase + r0) * KD + qt * 8;
    const unsigned short* a1p = A + (size_t)(rowbase + 64 + r0) * KD + qt * 8;

    f32x4 acc[2][4];
    #pragma unroll
    for (int mt = 0; mt < 2; mt++)
        #pragma unroll
        for (int nt = 0; nt < 4; nt++)
            acc[mt][nt] = (f32x4){0.f, 0.f, 0.f, 0.f};

    const int ml = l & 15, qd = l >> 4;
    for (int kk = 0; kk < KD; kk += 32) {
        __syncthreads();
        uint4 v0 = *(const uint4*)(a0p + kk);
        uint4 v1 = *(const uint4*)(a1p + kk);
        *(uint4*)(As + r0 * ASTR + qt * 8)        = v0;
        *(uint4*)(As + (64 + r0) * ASTR + qt * 8) = v1;
        {
            uint4 bv = *(const uint4*)(Bt_g + (size_t)(col0 + r0) * KD + kk + qt * 8);
            *(uint4*)(Bs + r0 * ASTR + qt * 8) = bv;
        }
        __syncthreads();
        bf16x8 a0 = *(const bf16x8*)(As + (w * 32 + ml) * ASTR + qd * 8);
        bf16x8 a1 = *(const bf16x8*)(As + (w * 32 + 16 + ml) * ASTR + qd * 8);
        #pragma unroll
        for (int nt = 0; nt < 4; nt++) {
            bf16x8 bb = *(const bf16x8*)(Bs + (nt * 16 + ml) * ASTR + qd * 8);
            acc[0][nt] = __builtin_amdgcn_mfma_f32_16x16x32_bf16(a0, bb, acc[0][nt], 0, 0, 0);
            acc[1][nt] = __builtin_amdgcn_mfma_f32_16x16x32_bf16(a1, bb, acc[1][nt], 0, 0, 0);
        }
    }

    #pragma unroll
    for (int nt = 0; nt < 4; nt++) {
        int col = col0 + nt * 16 + ml;
        float bv = bias[col];
        #pragma unroll
        for (int mt = 0; mt < 2; mt++) {
            int rl = w * 32 + mt * 16 + qd * 4;
            #pragma unroll
            for (int i = 0; i < 4; i++) {
                int row = rowbase + rl + i;
                float v = acc[mt][nt][i] + bv;
                if (EPI == 0) {
                    out_bf[(size_t)row * LDO + col] = f2bf(fmaxf(v, 0.f));
                } else if (EPI == 1) {
                    out_f[(size_t)row * CH + col] = v + res[(size_t)row * CH + col];
                } else if (EPI == 2) {
                    int qi = qidx[row];
                    out_f[(size_t)row * CH + col] = v + res[(size_t)qi * CH + col];
                } else {
                    out_f[(size_t)row * LDO + col] = v;
                }
            }
        }
    }
}

// ---------------------------------------------------------------------------
// k_attn3: staged-LDS fused attention. 2 queries/block; q/qp from qcat.
// ---------------------------------------------------------------------------
__global__ __launch_bounds__(256) void k_attn3(const float* __restrict__ qcat,
                                               const unsigned short* __restrict__ kvmat,
                                               const int* __restrict__ gidx,
                                               const int* __restrict__ mask_i,
                                               const int* __restrict__ rel_x,
                                               const int* __restrict__ rel_y,
                                               const int* __restrict__ rel_z,
                                               const float* __restrict__ comb,
                                               const float* __restrict__ b_v,
                                               unsigned short* __restrict__ attnln) {
    __shared__ float qc_s[2 * QCL];                 // q(256)+qp(320) per query; reused part 2
    __shared__ float attn_s[2 * 256];
    __shared__ int   mask_s[64];
    __shared__ int   gidx_s[64];
    __shared__ __align__(16) unsigned short ks[64 * KSTR];   // 33 KB

    int tid = threadIdx.x;
    int qb = blockIdx.x * 2;
    for (int i = tid; i < 2 * QCL; i += 256) qc_s[i] = qcat[(size_t)qb * QCL + i];
    if (tid < 64) {
        mask_s[tid] = mask_i[qb * 32 + tid];
        gidx_s[tid] = gidx[qb * 32 + tid];
    }
    __syncthreads();

    // ---- Phase A: stage k-parts (rows' first 512 B), coalesced ----
    const int srow = tid >> 5;                      // 0..7
    const int schk = tid & 31;                      // 16 B chunk within row
    uint4 kreg[8];
    #pragma unroll
    for (int j = 0; j < 8; j++) {
        int r = j * 8 + srow;
        uint4 v = {0u, 0u, 0u, 0u};
        if (!mask_s[r])
            v = *(const uint4*)(kvmat + (size_t)gidx_s[r] * 512 + schk * 8);
        kreg[j] = v;
    }
    #pragma unroll
    for (int j = 0; j < 8; j++)
        *(uint4*)(ks + (j * 8 + srow) * KSTR + schk * 8) = kreg[j];
    __syncthreads();

    // ---- Part 1: logits + softmax from LDS ----
    int h = tid >> 5, k = tid & 31;
    const float scale = 0.17677669529663687f;       // 32^-0.5
    for (int qq = 0; qq < 2; qq++) {
        int n = qb + qq;
        int gi = n * KN + k;
        int r = qq * 32 + k;
        int mk = mask_s[r];
        float lg = -1e9f;
        if (!mk) {
            int rx = rel_x[gi], ry = rel_y[gi], rz = rel_z[gi];
            const unsigned short* kp = ks + r * KSTR + h * 32;
            float kv[32];
            #pragma unroll
            for (int j = 0; j < 4; j++) {
                uint4 u = *(const uint4*)(kp + j * 8);
                kv[j * 8 + 0] = bf2f((unsigned short)(u.x & 0xFFFF));
                kv[j * 8 + 1] = bf2f((unsigned short)(u.x >> 16));
                kv[j * 8 + 2] = bf2f((unsigned short)(u.y & 0xFFFF));
                kv[j * 8 + 3] = bf2f((unsigned short)(u.y >> 16));
                kv[j * 8 + 4] = bf2f((unsigned short)(u.z & 0xFFFF));
                kv[j * 8 + 5] = bf2f((unsigned short)(u.z >> 16));
                kv[j * 8 + 6] = bf2f((unsigned short)(u.w & 0xFFFF));
                kv[j * 8 + 7] = bf2f((unsigned short)(u.w >> 16));
            }
            const float* cp = comb + ((((h * 15 + rx) * 15 + ry) * 7 + rz) << 5);
            float s1 = 0.f, s2 = 0.f;
            const float* qrow = qc_s + qq * QCL + h * DHD;
            #pragma unroll
            for (int d = 0; d < 32; d++) {
                s1 += kv[d] * qrow[d];
                s2 += kv[d] * cp[d];
            }
            lg = s1 * scale + s2
               + qc_s[qq * QCL + 256 + h * QPW + rx]
               + qc_s[qq * QCL + 256 + h * QPW + 15 + ry]
               + qc_s[qq * QCL + 256 + h * QPW + 30 + rz];
        }
        float mx = lg;
        #pragma unroll
        for (int off = 1; off <= 16; off <<= 1) mx = fmaxf(mx, __shfl_xor(mx, off));
        float e = mk ? 0.f : __expf(lg - mx);
        float sm = e;
        #pragma unroll
        for (int off = 1; off <= 16; off <<= 1) sm += __shfl_xor(sm, off);
        attn_s[qq * 256 + tid] = (sm > 0.f) ? e / sm : 0.f;
    }

    // ---- Phase B: restage v-parts into the same buffer ----
    #pragma unroll
    for (int j = 0; j < 8; j++) {
        int r = j * 8 + srow;
        uint4 v = {0u, 0u, 0u, 0u};
        if (!mask_s[r])
            v = *(const uint4*)(kvmat + (size_t)gidx_s[r] * 512 + 256 + schk * 8);
        kreg[j] = v;
    }
    __syncthreads();                                // part-1 ks/qc_s reads done
    #pragma unroll
    for (int j = 0; j < 8; j++)
        *(uint4*)(ks + (j * 8 + srow) * KSTR + schk * 8) = kreg[j];
    __syncthreads();

    // ---- Part 2: weighted v from LDS. wave w = (query w>>1, half w&1) ----
    int w = tid >> 6, l = tid & 63;
    int q2 = w >> 1, kh = w & 1;
    int hh = l >> 3;                                // head of col group l*4
    float a0 = 0.f, a1 = 0.f, a2 = 0.f, a3 = 0.f;
    #pragma unroll
    for (int i = 0; i < 16; i++) {
        int kk = kh * 16 + i;
        int r = q2 * 32 + kk;
        float av = attn_s[q2 * 256 + hh * 32 + kk]; // 0 for masked
        ushort4 v4 = *(const ushort4*)(ks + r * KSTR + l * 4);
        a0 += av * bf2f(v4.x);
        a1 += av * bf2f(v4.y);
        a2 += av * bf2f(v4.z);
        a3 += av * bf2f(v4.w);
    }
    if (kh == 1) {
        float4 pv = {a0, a1, a2, a3};
        *(float4*)(qc_s + q2 * 256 + l * 4) = pv;   // qc_s repurposed
    }
    __syncthreads();
    if (kh == 0) {
        float4 pv = *(const float4*)(qc_s + q2 * 256 + l * 4);
        a0 += pv.x; a1 += pv.y; a2 += pv.z; a3 += pv.w;
        int nm = 0;
        #pragma unroll
        for (int kk = 0; kk < 32; kk++) nm += 1 - mask_s[q2 * 32 + kk];
        int col = l * 4;
        if (nm == 0) {
            a0 = b_v[col]; a1 = b_v[col + 1]; a2 = b_v[col + 2]; a3 = b_v[col + 3];
        }
        ushort4 o;
        o.x = f2bf(a0); o.y = f2bf(a1); o.z = f2bf(a2); o.w = f2bf(a3);
        *(ushort4*)(attnln + (size_t)(qb + q2) * CH + col) = o;
    }
}

// ---------------------------------------------------------------------------
extern "C" void kernel_launch(void* const* d_in, const int* in_sizes, int n_in,
                              void* d_out, int out_size, void* d_ws, size_t ws_size,
                              hipStream_t stream) {
    (void)in_sizes; (void)n_in; (void)out_size; (void)ws_size;
    const float* vox    = (const float*)d_in[0];
    const float* coords = (const float*)d_in[1];
    const int*   qidx   = (const int*)d_in[2];
    const int*   gidx   = (const int*)d_in[3];
    const void*  mraw   = d_in[4];
    const int*   rel_x  = (const int*)d_in[5];
    const int*   rel_y  = (const int*)d_in[6];
    const int*   rel_z  = (const int*)d_in[7];
    const float* w_pos  = (const float*)d_in[8];
    const float* b_pos  = (const float*)d_in[9];
    const float* w_q    = (const float*)d_in[10];
    const float* b_q    = (const float*)d_in[11];
    const float* w_k    = (const float*)d_in[12];
    const float* b_k    = (const float*)d_in[13];
    const float* w_v    = (const float*)d_in[14];
    const float* b_v    = (const float*)d_in[15];
    const float* w_proj = (const float*)d_in[16];
    const float* b_proj = (const float*)d_in[17];
    const float* ln1_g  = (const float*)d_in[18];
    const float* ln1_b  = (const float*)d_in[19];
    const float* ln2_g  = (const float*)d_in[20];
    const float* ln2_b  = (const float*)d_in[21];
    const float* w_ff1  = (const float*)d_in[22];
    const float* b_ff1  = (const float*)d_in[23];
    const float* w_ff2  = (const float*)d_in[24];
    const float* b_ff2  = (const float*)d_in[25];
    const float* pos_qx = (const float*)d_in[26];
    const float* pos_qy = (const float*)d_in[27];
    const float* pos_qz = (const float*)d_in[28];
    const float* pos_kx = (const float*)d_in[29];
    const float* pos_ky = (const float*)d_in[30];
    const float* pos_kz = (const float*)d_in[31];

    // workspace carve (~210 MB total)
    char* p = (char*)d_ws;
    auto take = [&](size_t n) { char* r = p; p += (n + 255) & ~(size_t)255; return r; };
    unsigned short* ln_x    = (unsigned short*)take((size_t)MV * CH * 2);   // 51.2 MB
    unsigned short* w_kv_t  = (unsigned short*)take((size_t)512 * 256 * 2);
    unsigned short* w1_t    = (unsigned short*)take((size_t)512 * 256 * 2);
    unsigned short* w2_t    = (unsigned short*)take((size_t)256 * 512 * 2);
    unsigned short* wp_t    = (unsigned short*)take((size_t)256 * 256 * 2);
    unsigned short* wqcat   = (unsigned short*)take((size_t)QCL * 256 * 2); // 0.3 MB
    float*          bkv     = (float*)take(512 * 4);
    float*          bqcat   = (float*)take(QCL * 4);
    int*            flags   = (int*)take(64 * 4);
    int*            mask_i  = (int*)take((size_t)NG * 4);                   // 1.05 MB
    unsigned char*  touched = (unsigned char*)take(MV);                     // 0.1 MB
    float*          comb    = (float*)take((size_t)8 * 15 * 15 * 7 * 32 * 4); // 1.6 MB
    unsigned short* qin     = (unsigned short*)take((size_t)NQ * CH * 2);   // 4.2 MB
    float*          qcat    = (float*)take((size_t)NQ * QCL * 4);           // 18.9 MB
    unsigned short* kvmat   = (unsigned short*)take((size_t)MV * 512 * 2);  // 102.4 MB
    unsigned short* attnln  = (unsigned short*)take((size_t)NQ * CH * 2);   // 4.2 MB
    float*          actbuf  = (float*)take((size_t)NQ * CH * 4);            // 8.4 MB
    unsigned short* actln   = (unsigned short*)take((size_t)NQ * CH * 2);   // 4.2 MB
    unsigned short* hbuf    = (unsigned short*)take((size_t)NQ * FFD * 2);  // 8.4 MB

    hipMemsetAsync(touched, 0, MV, stream);
    hipLaunchKernelGGL(k_detect_mask, dim3(64), dim3(256), 0, stream,
                       (const unsigned char*)mraw, flags);
    hipLaunchKernelGGL(k_prep, dim3(NG / 256), dim3(256), 0, stream,
                       w_k, w_v, w_ff1, w_ff2, w_proj, w_q, b_k, b_v, b_q,
                       mraw, gidx, qidx, flags,
                       w_kv_t, w1_t, w2_t, wp_t, wqcat, bkv, bqcat,
                       mask_i, touched);
    hipLaunchKernelGGL(k_wqp, dim3(QCL - 256), dim3(256), 0, stream,
                       w_q, b_q, pos_qx, pos_qy, pos_qz, wqcat, bqcat);
    hipLaunchKernelGGL(k_posc, dim3((8 * 15 * 15 * 7 * 32 + 255) / 256), dim3(256), 0, stream,
                       pos_kx, pos_ky, pos_kz, comb);
    hipLaunchKernelGGL(k_ln, dim3(MV / 4 + 1), dim3(256), 0, stream,
                       vox, ln1_g, ln1_b, touched, ln_x, MV);
    hipLaunchKernelGGL(k_qin, dim3(NQ / 8), dim3(256), 0, stream,
                       ln_x, coords, qidx, w_pos, b_pos, qin);
    // dense kv projection: kv[m][512] = ln_x @ [w_k|w_v] + [b_k|b_v]
    hipLaunchKernelGGL(k_kv, dim3(4, (MV + 127) / 128), dim3(256), 0, stream,
                       ln_x, w_kv_t, bkv, touched, kvmat);
    // q‖qp = qin @ wqcat + bqcat  (fp32, ld QCL)
    hipLaunchKernelGGL(HIP_KERNEL_NAME(k_mm<256, 4, QCL>), dim3(QCL / 64, NQ / 128), dim3(256), 0, stream,
                       qin, wqcat, bqcat, (const float*)nullptr, (const int*)nullptr,
                       (unsigned short*)nullptr, qcat);
    // staged-LDS fused attention
    hipLaunchKernelGGL(k_attn3, dim3(NQ / 2), dim3(256), 0, stream,
                       qcat, kvmat, gidx, mask_i, rel_x, rel_y, rel_z,
                       comb, b_v, attnln);
    // proj: act = attn_bf16 @ wp_t + b_proj + vox[qidx]
    hipLaunchKernelGGL(HIP_KERNEL_NAME(k_mm<256, 2, CH>), dim3(4, NQ / 128), dim3(256), 0, stream,
                       attnln, wp_t, b_proj, vox, qidx,
                       (unsigned short*)nullptr, actbuf);
    hipLaunchKernelGGL(k_ln, dim3(NQ / 4), dim3(256), 0, stream,
                       actbuf, ln2_g, ln2_b, (const unsigned char*)nullptr, actln, NQ);
    // FF1: h = relu(actln @ w1_t + b_ff1)
    hipLaunchKernelGGL(HIP_KERNEL_NAME(k_mm<256, 0, FFD>), dim3(8, NQ / 128), dim3(256), 0, stream,
                       actln, w1_t, b_ff1, (const float*)nullptr, (const int*)nullptr,
                       hbuf, (float*)nullptr);
    // FF2: out = h @ w2_t + b_ff2 + act
    hipLaunchKernelGGL(HIP_KERNEL_NAME(k_mm<512, 1, CH>), dim3(4, NQ / 128), dim3(256), 0, stream,
                       hbuf, w2_t, b_ff2, actbuf, (const int*)nullptr,
                       (unsigned short*)nullptr, (float*)d_out);
}